// Round 14
// baseline (290.631 us; speedup 1.0000x reference)
//
#include <hip/hip_runtime.h>
#include <hip/hip_bf16.h>
#include <stdint.h>

#define B_ 2
#define C_ 512
#define G_ 4
#define D_ 128
#define N_ 4096

typedef __bf16 bf16;
typedef __bf16 bf16x8 __attribute__((ext_vector_type(8)));
typedef float  f32x4  __attribute__((ext_vector_type(4)));
typedef float  f32x16 __attribute__((ext_vector_type(16)));

#define MFMA   __builtin_amdgcn_mfma_f32_16x16x32_bf16
#define MFMA32 __builtin_amdgcn_mfma_f32_32x32x16_bf16

// LDS chunk swizzle for GEMMs: physical chunk = logical chunk ^ ((row>>1)&3)
#define SWZ(row, c) ((((c) ^ (((row) >> 1) & 3)) << 4))

// ---- workspace layout (bytes) ----
#define OFF_Q   (0u)           // [B*G][N][D] bf16 (pre-scaled by SC*log2e)
#define OFF_K   (8388608u)     // [B*G][N][D] bf16
#define OFF_VT  (16777216u)    // [B*G][D][N] bf16
#define OFF_XT  (25165824u)    // [B*N][C] bf16 (xT input; later attn O)
#define OFF_WB  (33554432u)    // 4 x [512][512] bf16
#define OFF_OP  (35651584u)    // bf16 [2][8][4096][128] partial O
#define OFF_ML  (52428800u)    // float2 [2][8][4096] running (m,l)
#define WS_NEED_SPLIT (52953088u)

__device__ inline unsigned pk2(float a, float b) {
    union { bf16 h[2]; unsigned u; } t;
    t.h[0] = (bf16)a; t.h[1] = (bf16)b;
    return t.u;
}
__device__ inline void pl32(unsigned &a, unsigned &b) {
    asm volatile("v_permlane32_swap_b32 %0, %1" : "+v"(a), "+v"(b));
}
__device__ inline void gload16(const char* src, char* lds) {
    __builtin_amdgcn_global_load_lds(
        (const __attribute__((address_space(1))) unsigned*)src,
        (__attribute__((address_space(3))) unsigned*)lds, 16, 0, 0);
}
__device__ inline float max3f(float a, float b, float c) {
    return fmaxf(fmaxf(a, b), c);   // clang fuses to v_max3_f32
}

// ---------- kernel 1: weights fp32 -> bf16 ----------
__global__ __launch_bounds__(256) void wcvt_kernel(const float* __restrict__ Wq,
                                                   const float* __restrict__ Wk,
                                                   const float* __restrict__ Wv,
                                                   const float* __restrict__ Wo,
                                                   bf16* __restrict__ out) {
    int m = blockIdx.y;
    const float* W = (m == 0) ? Wq : (m == 1) ? Wk : (m == 2) ? Wv : Wo;
    int i = (blockIdx.x * 256 + threadIdx.x) * 4;
    float4 v = *(const float4*)(W + i);
    union { bf16 h[4]; uint2 u; } pk;
    pk.h[0] = (bf16)v.x; pk.h[1] = (bf16)v.y; pk.h[2] = (bf16)v.z; pk.h[3] = (bf16)v.w;
    *(uint2*)(out + (size_t)m * (C_ * C_) + i) = pk.u;
}

// ---------- kernel 2: x [b][c][n] f32 -> xT [b*n][c] bf16 ----------
__global__ __launch_bounds__(256) void xt_kernel(const float* __restrict__ x,
                                                 bf16* __restrict__ xT) {
    __shared__ bf16 t[64 * 80];
    int n0 = blockIdx.x * 64, c0 = blockIdx.y * 64, b = blockIdx.z;
    const float* xp = x + (size_t)b * C_ * N_;
#pragma unroll
    for (int i = 0; i < 16; ++i) {
        int idx = threadIdx.x + 256 * i;
        int cl = idx >> 6, nl = idx & 63;
        float v = xp[(size_t)(c0 + cl) * N_ + n0 + nl];
        t[nl * 80 + cl] = (bf16)v;
    }
    __syncthreads();
    bf16* xt = xT + ((size_t)b * N_ + n0) * C_ + c0;
#pragma unroll
    for (int i = 0; i < 2; ++i) {
        int id = threadIdx.x + 256 * i;
        int nl = id >> 3, c8 = (id & 7) * 8;
        *(uint4*)(xt + (size_t)nl * C_ + c8) = *(const uint4*)(t + nl * 80 + c8);
    }
}

// ---------- kernel 3: fused QKV projection, 128x128 tile ----------
__global__ __launch_bounds__(256) void qkv_kernel(const bf16* __restrict__ xT,
                                                  const bf16* __restrict__ WB,
                                                  const float* __restrict__ bq,
                                                  const float* __restrict__ bk,
                                                  const float* __restrict__ bv,
                                                  bf16* __restrict__ Q,
                                                  bf16* __restrict__ K,
                                                  bf16* __restrict__ Vt) {
    __shared__ char smem[32768];
    const int tid = threadIdx.x;
    const int w = tid >> 6, l = tid & 63;
    const int lr = l & 15, lg = l >> 4;
    const int wr = w >> 1, wc = w & 1;
    const int mat = blockIdx.z;
    const bf16* A = xT;
    const bf16* W = WB + (size_t)mat * (C_ * C_);
    const float* bias = (mat == 0) ? bq : (mat == 1) ? bk : bv;
    const int r0 = blockIdx.x * 128, o0 = blockIdx.y * 128;
    const float QSCALE = 0.08838834764831845f * 1.4426950408889634f;

    const char* srcA[2]; const char* srcB[2]; int dA[2], dB[2];
#pragma unroll
    for (int i = 0; i < 2; ++i) {
        int CL = tid + 256 * i, row = CL >> 2, c = CL & 3;
        srcA[i] = (const char*)(A + (size_t)(r0 + row) * C_) + SWZ(row, c);
        srcB[i] = (const char*)(W + (size_t)(o0 + row) * C_) + SWZ(row, c);
        dA[i] = CL << 4;
        dB[i] = 8192 + (CL << 4);
    }

    f32x4 z = {0.f, 0.f, 0.f, 0.f};
    f32x4 acc[4][4];
#pragma unroll
    for (int m = 0; m < 4; ++m)
#pragma unroll
        for (int n = 0; n < 4; ++n) acc[m][n] = z;

    auto STAGE = [&](int buf, int kt) {
        char* base = smem + buf * 16384;
        int kb = kt * 64;
#pragma unroll
        for (int i = 0; i < 2; ++i) {
            gload16(srcA[i] + kb, base + dA[i]);
            gload16(srcB[i] + kb, base + dB[i]);
        }
    };

    STAGE(0, 0);
    __syncthreads();
#pragma unroll 4
    for (int t = 0; t < 16; ++t) {
        int cur = t & 1;
        if (t < 15) STAGE(cur ^ 1, t + 1);
        char* Ab = smem + cur * 16384;
        char* Bb = Ab + 8192;
        bf16x8 af[4], bg_[4];
#pragma unroll
        for (int m = 0; m < 4; ++m) {
            int row = wr * 64 + m * 16 + lr;
            af[m] = *(const bf16x8*)(Ab + row * 64 + SWZ(row, lg));
        }
#pragma unroll
        for (int n = 0; n < 4; ++n) {
            int row = wc * 64 + n * 16 + lr;
            bg_[n] = *(const bf16x8*)(Bb + row * 64 + SWZ(row, lg));
        }
#pragma unroll
        for (int m = 0; m < 4; ++m)
#pragma unroll
            for (int n = 0; n < 4; ++n)
                acc[m][n] = MFMA(af[m], bg_[n], acc[m][n], 0, 0, 0);
        __syncthreads();
    }

#pragma unroll
    for (int n = 0; n < 4; ++n) {
        int o = o0 + wc * 64 + n * 16 + lr;
        float bs = bias[o];
        int g = o >> 7, d = o & 127;
#pragma unroll
        for (int m = 0; m < 4; ++m) {
            int row = r0 + wr * 64 + m * 16 + lg * 4;
            int b = row >> 12, nn = row & (N_ - 1);
            if (mat == 0) {
#pragma unroll
                for (int j = 0; j < 4; ++j)
                    Q[((size_t)(b * G_ + g) * N_ + nn + j) * D_ + d] =
                        (bf16)((acc[m][n][j] + bs) * QSCALE);
            } else if (mat == 1) {
#pragma unroll
                for (int j = 0; j < 4; ++j)
                    K[((size_t)(b * G_ + g) * N_ + nn + j) * D_ + d] =
                        (bf16)(acc[m][n][j] + bs);
            } else {
                union { bf16 h[4]; uint2 u; } pk;
#pragma unroll
                for (int j = 0; j < 4; ++j) pk.h[j] = (bf16)(acc[m][n][j] + bs);
                *(uint2*)(Vt + ((size_t)(b * G_ + g) * D_ + d) * N_ + nn) = pk.u;
            }
        }
    }
}

// ---------- kernel 4: flash attention, K in registers (direct L2), V in LDS ----------
// 8 waves x 32 q = 256 q/block, grid 256 = 1 block/CU. K-fragment global address
// is LINEAR (swizzle cancels): kf0[kb] = K[(kv+l31)*128 + (2kb+h)*8]. K prefetched
// one tile ahead into regs; V double-buffered in 32KB LDS; ONE barrier per tile.
template<int SPLITS>
__global__ __launch_bounds__(512, 2) void attn_kernel(const bf16* __restrict__ Q,
                                                      const bf16* __restrict__ K,
                                                      const bf16* __restrict__ Vt,
                                                      bf16* __restrict__ XT,
                                                      bf16* __restrict__ Op,
                                                      float* __restrict__ ML) {
    __shared__ char smem[32768];   // V dbuf: 2 x 16KB
    const int tid = threadIdx.x;
    const int w = tid >> 6, l = tid & 63;
    const int l31 = l & 31, h = l >> 5;

    const int L = blockIdx.x;
    const int bg = L & 7;                       // head == XCD
    const int ix = L >> 3;
    const int sp = (SPLITS > 1) ? (ix >> 4) : 0;
    const int qb = (SPLITS > 1) ? (ix & 15) : ix;

    const bf16* Qh = Q + (size_t)bg * N_ * D_;
    const char* Kh = (const char*)(K + (size_t)bg * N_ * D_);
    const char* Vh = (const char*)(Vt + (size_t)bg * D_ * N_);
    const int q0 = qb * 256 + w * 32;
    const int kv0 = sp * (N_ / SPLITS);
    const int NT = N_ / SPLITS / 64;            // 16 (SPLITS=2), even

    // V staging offsets (2 x 16B per wave-lane, inverse-swizzled source)
    int offV[2];
#pragma unroll
    for (int j = 0; j < 2; ++j) {
        int CL = (w * 2 + j) * 64 + l;
        int row = CL >> 4;
        int cp = (CL & 15) ^ (row & 15);
        int dv = 2 * row + (cp >> 3), k8 = cp & 7;
        offV[j] = dv * (N_ * 2) + k8 * 16;
    }

    bf16x8 aq[8];
#pragma unroll
    for (int kb = 0; kb < 8; ++kb)
        aq[kb] = *(const bf16x8*)(Qh + (size_t)(q0 + l31) * D_ + kb * 16 + h * 8);

    bf16 one_ = (bf16)1.0f;
    bf16x8 ones = {one_, one_, one_, one_, one_, one_, one_, one_};

    f32x16 oacc[4], lacc;
#pragma unroll
    for (int dt = 0; dt < 4; ++dt)
#pragma unroll
        for (int r = 0; r < 16; ++r) oacc[dt][r] = 0.f;
#pragma unroll
    for (int r = 0; r < 16; ++r) lacc[r] = 0.f;
    float mrun = -1e30f;
    const float THR = 5.0f;

    auto STAGE_V = [&](int buf, int kv) {
        const char* pv = Vh + (size_t)kv * 2;
        char* vb = smem + buf * 16384 + w * 2048;
#pragma unroll
        for (int j = 0; j < 2; ++j) gload16(pv + offV[j], vb + j * 1024);
    };

    bf16x8 kA0[8], kA1[8], kB0[8], kB1[8];

#define LOADK(D0, D1, kvv)                                                        \
    _Pragma("unroll")                                                             \
    for (int kb = 0; kb < 8; ++kb) {                                              \
        D0[kb] = *(const bf16x8*)(Kh + (size_t)(kvv + l31) * 256 + (((kb << 1) | h) << 4));       \
        D1[kb] = *(const bf16x8*)(Kh + (size_t)(kvv + 32 + l31) * 256 + (((kb << 1) | h) << 4));  \
    }

    // prolog: V(0) lds + K(0) regs (issued; waits handled by counted vmcnt below)
    STAGE_V(0, kv0);
    LOADK(kA0, kA1, kv0)

#define BODY(KC0, KC1, KN0, KN1, P, T)                                            \
    {                                                                             \
        const int t_ = (T);                                                       \
        asm volatile("s_waitcnt vmcnt(16)" ::: "memory");  /* drain V(t) lds */   \
        __builtin_amdgcn_sched_barrier(0);                                        \
        __builtin_amdgcn_s_barrier();                       /* V(t) visible */    \
        if (t_ + 1 < NT) STAGE_V((P) ^ 1, kv0 + (t_ + 1) * 64);                   \
        if (t_ + 1 < NT) { LOADK(KN0, KN1, (kv0 + (t_ + 1) * 64)) }               \
        __builtin_amdgcn_sched_barrier(0);                                        \
        f32x16 s0, s1;                                                            \
        _Pragma("unroll") for (int r = 0; r < 16; ++r) { s0[r] = 0.f; s1[r] = 0.f; } \
        __builtin_amdgcn_s_setprio(1);                                            \
        _Pragma("unroll") for (int kb = 0; kb < 8; ++kb) {                        \
            s0 = MFMA32(KC0[kb], aq[kb], s0, 0, 0, 0);                            \
            s1 = MFMA32(KC1[kb], aq[kb], s1, 0, 0, 0);                            \
        }                                                                         \
        __builtin_amdgcn_s_setprio(0);                                            \
        float x0 = max3f(s0[0],  s0[1],  s0[2]);                                  \
        float x1 = max3f(s0[3],  s0[4],  s0[5]);                                  \
        float x2 = max3f(s0[6],  s0[7],  s0[8]);                                  \
        float x3 = max3f(s0[9],  s0[10], s0[11]);                                 \
        float x4 = max3f(s0[12], s0[13], s0[14]);                                 \
        float x5 = max3f(s0[15], s1[0],  s1[1]);                                  \
        float x6 = max3f(s1[2],  s1[3],  s1[4]);                                  \
        float x7 = max3f(s1[5],  s1[6],  s1[7]);                                  \
        float x8 = max3f(s1[8],  s1[9],  s1[10]);                                 \
        float x9 = max3f(s1[11], s1[12], s1[13]);                                 \
        float xa = fmaxf(s1[14], s1[15]);                                         \
        float y0 = max3f(x0, x1, x2);                                             \
        float y1 = max3f(x3, x4, x5);                                             \
        float y2 = max3f(x6, x7, x8);                                             \
        float y3 = fmaxf(x9, xa);                                                 \
        float mt = fmaxf(max3f(y0, y1, y2), y3);                                  \
        mt = fmaxf(mt, __shfl_xor(mt, 32));                                       \
        if (__any(mt > mrun + THR)) {                                             \
            float mn = fmaxf(mrun, mt);                                           \
            float corr = __builtin_amdgcn_exp2f(mrun - mn);                       \
            mrun = mn;                                                            \
            _Pragma("unroll") for (int r = 0; r < 16; ++r) {                      \
                int qr = (r & 3) + 8 * (r >> 2) + 4 * h;                          \
                float cr = __shfl(corr, qr);                                      \
                lacc[r] *= cr;                                                    \
                _Pragma("unroll") for (int dt = 0; dt < 4; ++dt) oacc[dt][r] *= cr; \
            }                                                                     \
        }                                                                         \
        _Pragma("unroll") for (int r = 0; r < 16; ++r) {                          \
            s0[r] = __builtin_amdgcn_exp2f(s0[r] - mrun);                         \
            s1[r] = __builtin_amdgcn_exp2f(s1[r] - mrun);                         \
        }                                                                         \
        bf16x8 pa0, pa1, pa2, pa3;                                                \
        {                                                                         \
            unsigned u0 = pk2(s0[0], s0[1]),  v0 = pk2(s0[4], s0[5]);  pl32(u0, v0); \
            unsigned u1 = pk2(s0[2], s0[3]),  v1 = pk2(s0[6], s0[7]);  pl32(u1, v1); \
            pa0 = __builtin_bit_cast(bf16x8, (uint4){u0, u1, v0, v1});            \
            unsigned u2 = pk2(s0[8], s0[9]),  v2 = pk2(s0[12], s0[13]); pl32(u2, v2); \
            unsigned u3 = pk2(s0[10], s0[11]), v3 = pk2(s0[14], s0[15]); pl32(u3, v3); \
            pa1 = __builtin_bit_cast(bf16x8, (uint4){u2, u3, v2, v3});            \
            unsigned u4 = pk2(s1[0], s1[1]),  v4 = pk2(s1[4], s1[5]);  pl32(u4, v4); \
            unsigned u5 = pk2(s1[2], s1[3]),  v5 = pk2(s1[6], s1[7]);  pl32(u5, v5); \
            pa2 = __builtin_bit_cast(bf16x8, (uint4){u4, u5, v4, v5});            \
            unsigned u6 = pk2(s1[8], s1[9]),  v6 = pk2(s1[12], s1[13]); pl32(u6, v6); \
            unsigned u7 = pk2(s1[10], s1[11]), v7 = pk2(s1[14], s1[15]); pl32(u7, v7); \
            pa3 = __builtin_bit_cast(bf16x8, (uint4){u6, u7, v6, v7});            \
        }                                                                         \
        char* Vb = smem + (P) * 16384;                                            \
        __builtin_amdgcn_s_setprio(1);                                            \
        _Pragma("unroll") for (int sl = 0; sl < 4; ++sl) {                        \
            bf16x8 pa = (sl == 0) ? pa0 : (sl == 1) ? pa1 : (sl == 2) ? pa2 : pa3; \
            _Pragma("unroll") for (int dt = 0; dt < 4; ++dt) {                    \
                int row = dt * 16 + (l31 >> 1);                                   \
                int ch = ((((l31 & 1) << 3) + (sl << 1) + h) ^ (l31 >> 1)) << 4;  \
                bf16x8 vf = *(const bf16x8*)(Vb + (size_t)row * 256 + ch);        \
                oacc[dt] = MFMA32(pa, vf, oacc[dt], 0, 0, 0);                     \
            }                                                                     \
            lacc = MFMA32(pa, ones, lacc, 0, 0, 0);                               \
        }                                                                         \
        __builtin_amdgcn_s_setprio(0);                                            \
    }

    for (int t2 = 0; t2 < NT; t2 += 2) {
        BODY(kA0, kA1, kB0, kB1, 0, t2)
        BODY(kB0, kB1, kA0, kA1, 1, t2 + 1)
    }
#undef BODY
#undef LOADK

    // ---- epilogue ----
    if (SPLITS > 1) {
        float2* mlp = (float2*)ML + ((size_t)sp * 8 + bg) * N_ + q0;
#pragma unroll
        for (int r = 0; r < 16; ++r) {
            int qr = (r & 3) + 8 * (r >> 2) + 4 * h;
            float mv = __shfl(mrun, qr);
            if (l31 == 0) {
                float2 v; v.x = mv; v.y = lacc[r];
                mlp[qr] = v;
            }
        }
        bf16* op = Op + (((size_t)sp * 8 + bg) * N_ + q0) * D_;
#pragma unroll
        for (int dt = 0; dt < 4; ++dt)
#pragma unroll
            for (int r = 0; r < 16; ++r) {
                int qr = (r & 3) + 8 * (r >> 2) + 4 * h;
                op[(size_t)qr * D_ + dt * 32 + l31] = (bf16)oacc[dt][r];
            }
    } else {
        int b = bg >> 2, g = bg & 3;
#pragma unroll
        for (int r = 0; r < 16; ++r) {
            int qr = (r & 3) + 8 * (r >> 2) + 4 * h;
            float iv = 1.f / lacc[r];
#pragma unroll
            for (int dt = 0; dt < 4; ++dt)
                XT[((size_t)b * N_ + q0 + qr) * C_ + g * D_ + dt * 32 + l31] =
                    (bf16)(oacc[dt][r] * iv);
        }
    }
}

// ---------- kernel 4b: merge the 2 KV-split partials ----------
__global__ __launch_bounds__(256) void merge_kernel(const bf16* __restrict__ Op,
                                                    const float* __restrict__ ML,
                                                    bf16* __restrict__ XT) {
    int t = threadIdx.x & 15, rl = threadIdx.x >> 4;
    int r = blockIdx.x * 16 + rl;
    int bg = r >> 12, n = r & (N_ - 1);
    const float2* mlp = (const float2*)ML;
    float2 ml0 = mlp[r], ml1 = mlp[32768 + r];
    float mm = fmaxf(ml0.x, ml1.x);
    float w0 = __builtin_amdgcn_exp2f(ml0.x - mm);
    float w1 = __builtin_amdgcn_exp2f(ml1.x - mm);
    float inv = 1.f / (w0 * ml0.y + w1 * ml1.y);
    w0 *= inv; w1 *= inv;
    bf16x8 o0 = *(const bf16x8*)(Op + (size_t)r * D_ + t * 8);
    bf16x8 o1 = *(const bf16x8*)(Op + (size_t)(32768 + r) * D_ + t * 8);
    union { bf16 h[8]; uint4 u; } pk;
#pragma unroll
    for (int e = 0; e < 8; ++e)
        pk.h[e] = (bf16)(w0 * (float)o0[e] + w1 * (float)o1[e]);
    int b = bg >> 2, g = bg & 3;
    *(uint4*)(XT + ((size_t)b * N_ + n) * C_ + g * D_ + t * 8) = pk.u;
}

// ---------- kernel 5: output projection, 128x64 tile ----------
__global__ __launch_bounds__(256) void oproj_kernel(const bf16* __restrict__ Ob,
                                                    const bf16* __restrict__ WB,
                                                    const float* __restrict__ bo,
                                                    const float* __restrict__ x,
                                                    float* __restrict__ out) {
    __shared__ char smem[24576];
    const int tid = threadIdx.x;
    const int w = tid >> 6, l = tid & 63;
    const int lr = l & 15, lg = l >> 4;
    const int wr = w >> 1, wc = w & 1;
    const bf16* W = WB + (size_t)3 * (C_ * C_);
    const int r0 = blockIdx.x * 128, o0 = blockIdx.y * 64;

    const char* srcA[2]; int dA[2];
#pragma unroll
    for (int i = 0; i < 2; ++i) {
        int CL = tid + 256 * i, row = CL >> 2, c = CL & 3;
        srcA[i] = (const char*)(Ob + (size_t)(r0 + row) * C_) + SWZ(row, c);
        dA[i] = CL << 4;
    }
    const char* srcB; int dB;
    {
        int CL = tid, row = CL >> 2, c = CL & 3;
        srcB = (const char*)(W + (size_t)(o0 + row) * C_) + SWZ(row, c);
        dB = 8192 + (CL << 4);
    }

    f32x4 z = {0.f, 0.f, 0.f, 0.f};
    f32x4 acc[4][2];
#pragma unroll
    for (int m = 0; m < 4; ++m) { acc[m][0] = z; acc[m][1] = z; }

    auto STAGE = [&](int buf, int kt) {
        char* base = smem + buf * 12288;
        int kb = kt * 64;
#pragma unroll
        for (int i = 0; i < 2; ++i) gload16(srcA[i] + kb, base + dA[i]);
        gload16(srcB + kb, base + dB);
    };

    STAGE(0, 0);
    __syncthreads();
#pragma unroll 4
    for (int t = 0; t < 16; ++t) {
        int cur = t & 1;
        if (t < 15) STAGE(cur ^ 1, t + 1);
        char* Ab = smem + cur * 12288;
        char* Bb = Ab + 8192;
        bf16x8 af[4], bg_[2];
#pragma unroll
        for (int m = 0; m < 4; ++m) {
            int row = wr * 64 + m * 16 + lr;
            af[m] = *(const bf16x8*)(Ab + row * 64 + SWZ(row, lg));
        }
#pragma unroll
        for (int n = 0; n < 2; ++n) {
            int row = wc * 32 + n * 16 + lr;
            bg_[n] = *(const bf16x8*)(Bb + row * 64 + SWZ(row, lg));
        }
#pragma unroll
        for (int m = 0; m < 4; ++m)
#pragma unroll
            for (int n = 0; n < 2; ++n)
                acc[m][n] = MFMA(af[m], bg_[n], acc[m][n], 0, 0, 0);
        __syncthreads();
    }

#pragma unroll
    for (int n = 0; n < 2; ++n) {
        int o = o0 + wc * 32 + n * 16 + lr;
        float bs = bo[o];
#pragma unroll
        for (int m = 0; m < 4; ++m) {
            int row = r0 + wr * 64 + m * 16 + lg * 4;
            int b = row >> 12, nn = row & (N_ - 1);
            size_t base = ((size_t)b * C_ + o) * N_ + nn;
            float4 xv = *(const float4*)(x + base);
            float4 ov;
            ov.x = acc[m][n][0] + bs + xv.x;
            ov.y = acc[m][n][1] + bs + xv.y;
            ov.z = acc[m][n][2] + bs + xv.z;
            ov.w = acc[m][n][3] + bs + xv.w;
            *(float4*)(out + base) = ov;
        }
    }
}

extern "C" void kernel_launch(void* const* d_in, const int* in_sizes, int n_in,
                              void* d_out, int out_size, void* d_ws, size_t ws_size,
                              hipStream_t stream) {
    const float* x  = (const float*)d_in[0];
    const float* Wq = (const float*)d_in[1];
    const float* bq = (const float*)d_in[2];
    const float* Wk = (const float*)d_in[3];
    const float* bk = (const float*)d_in[4];
    const float* Wv = (const float*)d_in[5];
    const float* bv = (const float*)d_in[6];
    const float* Wo = (const float*)d_in[7];
    const float* bo = (const float*)d_in[8];

    char* ws = (char*)d_ws;
    bf16* Q   = (bf16*)(ws + OFF_Q);
    bf16* K   = (bf16*)(ws + OFF_K);
    bf16* Vt  = (bf16*)(ws + OFF_VT);
    bf16* XT  = (bf16*)(ws + OFF_XT);
    bf16* WB  = (bf16*)(ws + OFF_WB);
    bf16* Op  = (bf16*)(ws + OFF_OP);
    float* ML = (float*)(ws + OFF_ML);
    float* out = (float*)d_out;

    hipLaunchKernelGGL(wcvt_kernel, dim3(256, 4), dim3(256), 0, stream, Wq, Wk, Wv, Wo, WB);
    hipLaunchKernelGGL(xt_kernel, dim3(64, 8, 2), dim3(256), 0, stream, x, XT);
    hipLaunchKernelGGL(qkv_kernel, dim3(64, 4, 3), dim3(256), 0, stream,
                       XT, WB, bq, bk, bv, Q, K, Vt);
    if (ws_size >= (size_t)WS_NEED_SPLIT) {
        hipLaunchKernelGGL(attn_kernel<2>, dim3(256), dim3(512), 0, stream,
                           Q, K, Vt, XT, Op, ML);
        hipLaunchKernelGGL(merge_kernel, dim3(2048), dim3(256), 0, stream, Op, ML, XT);
    } else {
        hipLaunchKernelGGL(attn_kernel<1>, dim3(128), dim3(512), 0, stream,
                           Q, K, Vt, XT, Op, ML);
    }
    hipLaunchKernelGGL(oproj_kernel, dim3(64, 8), dim3(256), 0, stream, XT, WB, bo, x, out);
}

// Round 15
// 237.872 us; speedup vs baseline: 1.2218x; 1.2218x over previous
//
#include <hip/hip_runtime.h>
#include <hip/hip_bf16.h>
#include <stdint.h>

#define B_ 2
#define C_ 512
#define G_ 4
#define D_ 128
#define N_ 4096

typedef __bf16 bf16;
typedef __bf16 bf16x8 __attribute__((ext_vector_type(8)));
typedef float  f32x4  __attribute__((ext_vector_type(4)));
typedef float  f32x16 __attribute__((ext_vector_type(16)));

#define MFMA   __builtin_amdgcn_mfma_f32_16x16x32_bf16
#define MFMA32 __builtin_amdgcn_mfma_f32_32x32x16_bf16

// LDS chunk swizzle for GEMMs: physical chunk = logical chunk ^ ((row>>1)&3)
#define SWZ(row, c) ((((c) ^ (((row) >> 1) & 3)) << 4))

// ---- workspace layout (bytes) ----
#define OFF_Q   (0u)           // [B*G][N][D] bf16 (pre-scaled by SC*log2e)
#define OFF_K   (8388608u)     // [B*G][N][D] bf16
#define OFF_VT  (16777216u)    // [B*G][D][N] bf16
#define OFF_XT  (25165824u)    // [B*N][C] bf16 (xT input; later attn O)
#define OFF_WB  (33554432u)    // 4 x [512][512] bf16
#define OFF_OP  (35651584u)    // bf16 [2][8][4096][128] partial O
#define OFF_ML  (52428800u)    // float2 [2][8][4096] running (m,l)
#define WS_NEED_SPLIT (52953088u)

__device__ inline unsigned pk2(float a, float b) {
    union { bf16 h[2]; unsigned u; } t;
    t.h[0] = (bf16)a; t.h[1] = (bf16)b;
    return t.u;
}
__device__ inline void pl32(unsigned &a, unsigned &b) {
    asm volatile("v_permlane32_swap_b32 %0, %1" : "+v"(a), "+v"(b));
}
__device__ inline void gload16(const char* src, char* lds) {
    __builtin_amdgcn_global_load_lds(
        (const __attribute__((address_space(1))) unsigned*)src,
        (__attribute__((address_space(3))) unsigned*)lds, 16, 0, 0);
}
__device__ inline float max3f(float a, float b, float c) {
    return fmaxf(fmaxf(a, b), c);   // clang fuses to v_max3_f32
}

// ---------- kernel 1: weights fp32 -> bf16 ----------
__global__ __launch_bounds__(256) void wcvt_kernel(const float* __restrict__ Wq,
                                                   const float* __restrict__ Wk,
                                                   const float* __restrict__ Wv,
                                                   const float* __restrict__ Wo,
                                                   bf16* __restrict__ out) {
    int m = blockIdx.y;
    const float* W = (m == 0) ? Wq : (m == 1) ? Wk : (m == 2) ? Wv : Wo;
    int i = (blockIdx.x * 256 + threadIdx.x) * 4;
    float4 v = *(const float4*)(W + i);
    union { bf16 h[4]; uint2 u; } pk;
    pk.h[0] = (bf16)v.x; pk.h[1] = (bf16)v.y; pk.h[2] = (bf16)v.z; pk.h[3] = (bf16)v.w;
    *(uint2*)(out + (size_t)m * (C_ * C_) + i) = pk.u;
}

// ---------- kernel 2: x [b][c][n] f32 -> xT [b*n][c] bf16 ----------
__global__ __launch_bounds__(256) void xt_kernel(const float* __restrict__ x,
                                                 bf16* __restrict__ xT) {
    __shared__ bf16 t[64 * 80];
    int n0 = blockIdx.x * 64, c0 = blockIdx.y * 64, b = blockIdx.z;
    const float* xp = x + (size_t)b * C_ * N_;
#pragma unroll
    for (int i = 0; i < 16; ++i) {
        int idx = threadIdx.x + 256 * i;
        int cl = idx >> 6, nl = idx & 63;
        float v = xp[(size_t)(c0 + cl) * N_ + n0 + nl];
        t[nl * 80 + cl] = (bf16)v;
    }
    __syncthreads();
    bf16* xt = xT + ((size_t)b * N_ + n0) * C_ + c0;
#pragma unroll
    for (int i = 0; i < 2; ++i) {
        int id = threadIdx.x + 256 * i;
        int nl = id >> 3, c8 = (id & 7) * 8;
        *(uint4*)(xt + (size_t)nl * C_ + c8) = *(const uint4*)(t + nl * 80 + c8);
    }
}

// ---------- kernel 3: fused QKV projection, 128x128 tile ----------
__global__ __launch_bounds__(256) void qkv_kernel(const bf16* __restrict__ xT,
                                                  const bf16* __restrict__ WB,
                                                  const float* __restrict__ bq,
                                                  const float* __restrict__ bk,
                                                  const float* __restrict__ bv,
                                                  bf16* __restrict__ Q,
                                                  bf16* __restrict__ K,
                                                  bf16* __restrict__ Vt) {
    __shared__ char smem[32768];
    const int tid = threadIdx.x;
    const int w = tid >> 6, l = tid & 63;
    const int lr = l & 15, lg = l >> 4;
    const int wr = w >> 1, wc = w & 1;
    const int mat = blockIdx.z;
    const bf16* A = xT;
    const bf16* W = WB + (size_t)mat * (C_ * C_);
    const float* bias = (mat == 0) ? bq : (mat == 1) ? bk : bv;
    const int r0 = blockIdx.x * 128, o0 = blockIdx.y * 128;
    const float QSCALE = 0.08838834764831845f * 1.4426950408889634f;

    const char* srcA[2]; const char* srcB[2]; int dA[2], dB[2];
#pragma unroll
    for (int i = 0; i < 2; ++i) {
        int CL = tid + 256 * i, row = CL >> 2, c = CL & 3;
        srcA[i] = (const char*)(A + (size_t)(r0 + row) * C_) + SWZ(row, c);
        srcB[i] = (const char*)(W + (size_t)(o0 + row) * C_) + SWZ(row, c);
        dA[i] = CL << 4;
        dB[i] = 8192 + (CL << 4);
    }

    f32x4 z = {0.f, 0.f, 0.f, 0.f};
    f32x4 acc[4][4];
#pragma unroll
    for (int m = 0; m < 4; ++m)
#pragma unroll
        for (int n = 0; n < 4; ++n) acc[m][n] = z;

    auto STAGE = [&](int buf, int kt) {
        char* base = smem + buf * 16384;
        int kb = kt * 64;
#pragma unroll
        for (int i = 0; i < 2; ++i) {
            gload16(srcA[i] + kb, base + dA[i]);
            gload16(srcB[i] + kb, base + dB[i]);
        }
    };

    STAGE(0, 0);
    __syncthreads();
#pragma unroll 4
    for (int t = 0; t < 16; ++t) {
        int cur = t & 1;
        if (t < 15) STAGE(cur ^ 1, t + 1);
        char* Ab = smem + cur * 16384;
        char* Bb = Ab + 8192;
        bf16x8 af[4], bg_[4];
#pragma unroll
        for (int m = 0; m < 4; ++m) {
            int row = wr * 64 + m * 16 + lr;
            af[m] = *(const bf16x8*)(Ab + row * 64 + SWZ(row, lg));
        }
#pragma unroll
        for (int n = 0; n < 4; ++n) {
            int row = wc * 64 + n * 16 + lr;
            bg_[n] = *(const bf16x8*)(Bb + row * 64 + SWZ(row, lg));
        }
#pragma unroll
        for (int m = 0; m < 4; ++m)
#pragma unroll
            for (int n = 0; n < 4; ++n)
                acc[m][n] = MFMA(af[m], bg_[n], acc[m][n], 0, 0, 0);
        __syncthreads();
    }

#pragma unroll
    for (int n = 0; n < 4; ++n) {
        int o = o0 + wc * 64 + n * 16 + lr;
        float bs = bias[o];
        int g = o >> 7, d = o & 127;
#pragma unroll
        for (int m = 0; m < 4; ++m) {
            int row = r0 + wr * 64 + m * 16 + lg * 4;
            int b = row >> 12, nn = row & (N_ - 1);
            if (mat == 0) {
#pragma unroll
                for (int j = 0; j < 4; ++j)
                    Q[((size_t)(b * G_ + g) * N_ + nn + j) * D_ + d] =
                        (bf16)((acc[m][n][j] + bs) * QSCALE);
            } else if (mat == 1) {
#pragma unroll
                for (int j = 0; j < 4; ++j)
                    K[((size_t)(b * G_ + g) * N_ + nn + j) * D_ + d] =
                        (bf16)(acc[m][n][j] + bs);
            } else {
                union { bf16 h[4]; uint2 u; } pk;
#pragma unroll
                for (int j = 0; j < 4; ++j) pk.h[j] = (bf16)(acc[m][n][j] + bs);
                *(uint2*)(Vt + ((size_t)(b * G_ + g) * D_ + d) * N_ + nn) = pk.u;
            }
        }
    }
}

// ---------- kernel 4: flash attention, single-buffered K-in-regs, V in LDS ----------
// 8 waves x 32 q = 256 q/block, grid 256 = 1 block/CU. K loaded per-tile directly
// from L2 into 64 VGPRs (linear address, verified r14); dead after S-MFMA -> no
// spill. LDS = V dbuf only (32KB) -> LDS-port traffic halved vs r13.
template<int SPLITS>
__global__ __launch_bounds__(512, 2) void attn_kernel(const bf16* __restrict__ Q,
                                                      const bf16* __restrict__ K,
                                                      const bf16* __restrict__ Vt,
                                                      bf16* __restrict__ XT,
                                                      bf16* __restrict__ Op,
                                                      float* __restrict__ ML) {
    __shared__ char smem[32768];   // V dbuf: 2 x 16KB
    const int tid = threadIdx.x;
    const int w = tid >> 6, l = tid & 63;
    const int l31 = l & 31, h = l >> 5;

    const int L = blockIdx.x;
    const int bg = L & 7;                       // head == XCD
    const int ix = L >> 3;
    const int sp = (SPLITS > 1) ? (ix >> 4) : 0;
    const int qb = (SPLITS > 1) ? (ix & 15) : ix;

    const bf16* Qh = Q + (size_t)bg * N_ * D_;
    const char* Kh = (const char*)(K + (size_t)bg * N_ * D_);
    const char* Vh = (const char*)(Vt + (size_t)bg * D_ * N_);
    const int q0 = qb * 256 + w * 32;
    const int kv0 = sp * (N_ / SPLITS);
    const int NT = N_ / SPLITS / 64;

    // V staging offsets (2 x 16B per lane, inverse-swizzled source)
    int offV[2];
#pragma unroll
    for (int j = 0; j < 2; ++j) {
        int CL = (w * 2 + j) * 64 + l;
        int row = CL >> 4;
        int cp = (CL & 15) ^ (row & 15);
        int dv = 2 * row + (cp >> 3), k8 = cp & 7;
        offV[j] = dv * (N_ * 2) + k8 * 16;
    }

    bf16x8 aq[8];
#pragma unroll
    for (int kb = 0; kb < 8; ++kb)
        aq[kb] = *(const bf16x8*)(Qh + (size_t)(q0 + l31) * D_ + kb * 16 + h * 8);

    bf16 one_ = (bf16)1.0f;
    bf16x8 ones = {one_, one_, one_, one_, one_, one_, one_, one_};

    f32x16 oacc[4], lacc;
#pragma unroll
    for (int dt = 0; dt < 4; ++dt)
#pragma unroll
        for (int r = 0; r < 16; ++r) oacc[dt][r] = 0.f;
#pragma unroll
    for (int r = 0; r < 16; ++r) lacc[r] = 0.f;
    float mrun = -1e30f;
    const float THR = 5.0f;

    auto STAGE_V = [&](int buf, int kv) {
        const char* pv = Vh + (size_t)kv * 2;
        char* vb = smem + buf * 16384 + w * 2048;
#pragma unroll
        for (int j = 0; j < 2; ++j) gload16(pv + offV[j], vb + j * 1024);
    };

    STAGE_V(0, kv0);

    for (int t = 0; t < NT; ++t) {
        int cur = t & 1;
        int kv = kv0 + t * 64;
        __builtin_amdgcn_s_barrier();           // B1: all waves done reading V(t-1)

        // K(t) -> regs (16 loads, linear addresses), then V(t+1) staging
        bf16x8 kf0[8], kf1[8];
#pragma unroll
        for (int kb = 0; kb < 8; ++kb) {
            kf0[kb] = *(const bf16x8*)(Kh + (size_t)(kv + l31) * 256 + (((kb << 1) | h) << 4));
            kf1[kb] = *(const bf16x8*)(Kh + (size_t)(kv + 32 + l31) * 256 + (((kb << 1) | h) << 4));
        }
        if (t + 1 < NT) {
            STAGE_V(cur ^ 1, kv + 64);
            // order: [V(t):2][K(t):16][V(t+1):2] -> vmcnt(2) drains V(t)+K(t)
            asm volatile("s_waitcnt vmcnt(2)" ::: "memory");
        } else {
            asm volatile("s_waitcnt vmcnt(0)" ::: "memory");
        }
        __builtin_amdgcn_sched_barrier(0);
        __builtin_amdgcn_s_barrier();           // B2: V(t) visible block-wide
        char* Vb = smem + cur * 16384;

        // ---- S^T = K Q^T (pure register MFMA) ----
        f32x16 s0, s1;
#pragma unroll
        for (int r = 0; r < 16; ++r) { s0[r] = 0.f; s1[r] = 0.f; }
        __builtin_amdgcn_s_setprio(1);
#pragma unroll
        for (int kb = 0; kb < 8; ++kb) {
            s0 = MFMA32(kf0[kb], aq[kb], s0, 0, 0, 0);
            s1 = MFMA32(kf1[kb], aq[kb], s1, 0, 0, 0);
        }
        __builtin_amdgcn_s_setprio(0);

        // ---- tile max via max3 tree (lane owns q = l31) ----
        float x0 = max3f(s0[0],  s0[1],  s0[2]);
        float x1 = max3f(s0[3],  s0[4],  s0[5]);
        float x2 = max3f(s0[6],  s0[7],  s0[8]);
        float x3 = max3f(s0[9],  s0[10], s0[11]);
        float x4 = max3f(s0[12], s0[13], s0[14]);
        float x5 = max3f(s0[15], s1[0],  s1[1]);
        float x6 = max3f(s1[2],  s1[3],  s1[4]);
        float x7 = max3f(s1[5],  s1[6],  s1[7]);
        float x8 = max3f(s1[8],  s1[9],  s1[10]);
        float x9 = max3f(s1[11], s1[12], s1[13]);
        float xa = fmaxf(s1[14], s1[15]);
        float y0 = max3f(x0, x1, x2);
        float y1 = max3f(x3, x4, x5);
        float y2 = max3f(x6, x7, x8);
        float y3 = fmaxf(x9, xa);
        float mt = fmaxf(max3f(y0, y1, y2), y3);
        mt = fmaxf(mt, __shfl_xor(mt, 32));

        if (__any(mt > mrun + THR)) {
            float mn = fmaxf(mrun, mt);
            float corr = __builtin_amdgcn_exp2f(mrun - mn);
            mrun = mn;
#pragma unroll
            for (int r = 0; r < 16; ++r) {
                int qr = (r & 3) + 8 * (r >> 2) + 4 * h;
                float cr = __shfl(corr, qr);
                lacc[r] *= cr;
#pragma unroll
                for (int dt = 0; dt < 4; ++dt) oacc[dt][r] *= cr;
            }
        }

#pragma unroll
        for (int r = 0; r < 16; ++r) {
            s0[r] = __builtin_amdgcn_exp2f(s0[r] - mrun);
            s1[r] = __builtin_amdgcn_exp2f(s1[r] - mrun);
        }

        // ---- P -> bf16 PV A-fragments via pack + permlane32_swap ----
        bf16x8 pa0, pa1, pa2, pa3;
        {
            unsigned x0_ = pk2(s0[0], s0[1]),  y0_ = pk2(s0[4], s0[5]);  pl32(x0_, y0_);
            unsigned x1_ = pk2(s0[2], s0[3]),  y1_ = pk2(s0[6], s0[7]);  pl32(x1_, y1_);
            pa0 = __builtin_bit_cast(bf16x8, (uint4){x0_, x1_, y0_, y1_});
            unsigned x2_ = pk2(s0[8], s0[9]),  y2_ = pk2(s0[12], s0[13]); pl32(x2_, y2_);
            unsigned x3_ = pk2(s0[10], s0[11]), y3_ = pk2(s0[14], s0[15]); pl32(x3_, y3_);
            pa1 = __builtin_bit_cast(bf16x8, (uint4){x2_, x3_, y2_, y3_});
            unsigned x4_ = pk2(s1[0], s1[1]),  y4_ = pk2(s1[4], s1[5]);  pl32(x4_, y4_);
            unsigned x5_ = pk2(s1[2], s1[3]),  y5_ = pk2(s1[6], s1[7]);  pl32(x5_, y5_);
            pa2 = __builtin_bit_cast(bf16x8, (uint4){x4_, x5_, y4_, y5_});
            unsigned x6_ = pk2(s1[8], s1[9]),  y6_ = pk2(s1[12], s1[13]); pl32(x6_, y6_);
            unsigned x7_ = pk2(s1[10], s1[11]), y7_ = pk2(s1[14], s1[15]); pl32(x7_, y7_);
            pa3 = __builtin_bit_cast(bf16x8, (uint4){x6_, x7_, y6_, y7_});
        }

        // ---- O += P V ; l += P 1 (row-sum on the MFMA pipe) ----
        __builtin_amdgcn_s_setprio(1);
#pragma unroll
        for (int sl = 0; sl < 4; ++sl) {
            bf16x8 pa = (sl == 0) ? pa0 : (sl == 1) ? pa1 : (sl == 2) ? pa2 : pa3;
#pragma unroll
            for (int dt = 0; dt < 4; ++dt) {
                int row = dt * 16 + (l31 >> 1);
                int ch = ((((l31 & 1) << 3) + (sl << 1) + h) ^ (l31 >> 1)) << 4;
                bf16x8 vf = *(const bf16x8*)(Vb + (size_t)row * 256 + ch);
                oacc[dt] = MFMA32(pa, vf, oacc[dt], 0, 0, 0);
            }
            lacc = MFMA32(pa, ones, lacc, 0, 0, 0);
        }
        __builtin_amdgcn_s_setprio(0);
    }

    // ---- epilogue ----
    if (SPLITS > 1) {
        float2* mlp = (float2*)ML + ((size_t)sp * 8 + bg) * N_ + q0;
#pragma unroll
        for (int r = 0; r < 16; ++r) {
            int qr = (r & 3) + 8 * (r >> 2) + 4 * h;
            float mv = __shfl(mrun, qr);
            if (l31 == 0) {
                float2 v; v.x = mv; v.y = lacc[r];
                mlp[qr] = v;
            }
        }
        bf16* op = Op + (((size_t)sp * 8 + bg) * N_ + q0) * D_;
#pragma unroll
        for (int dt = 0; dt < 4; ++dt)
#pragma unroll
            for (int r = 0; r < 16; ++r) {
                int qr = (r & 3) + 8 * (r >> 2) + 4 * h;
                op[(size_t)qr * D_ + dt * 32 + l31] = (bf16)oacc[dt][r];
            }
    } else {
        int b = bg >> 2, g = bg & 3;
#pragma unroll
        for (int r = 0; r < 16; ++r) {
            int qr = (r & 3) + 8 * (r >> 2) + 4 * h;
            float iv = 1.f / lacc[r];
#pragma unroll
            for (int dt = 0; dt < 4; ++dt)
                XT[((size_t)b * N_ + q0 + qr) * C_ + g * D_ + dt * 32 + l31] =
                    (bf16)(oacc[dt][r] * iv);
        }
    }
}

// ---------- kernel 4b: merge the 2 KV-split partials ----------
__global__ __launch_bounds__(256) void merge_kernel(const bf16* __restrict__ Op,
                                                    const float* __restrict__ ML,
                                                    bf16* __restrict__ XT) {
    int t = threadIdx.x & 15, rl = threadIdx.x >> 4;
    int r = blockIdx.x * 16 + rl;
    int bg = r >> 12, n = r & (N_ - 1);
    const float2* mlp = (const float2*)ML;
    float2 ml0 = mlp[r], ml1 = mlp[32768 + r];
    float mm = fmaxf(ml0.x, ml1.x);
    float w0 = __builtin_amdgcn_exp2f(ml0.x - mm);
    float w1 = __builtin_amdgcn_exp2f(ml1.x - mm);
    float inv = 1.f / (w0 * ml0.y + w1 * ml1.y);
    w0 *= inv; w1 *= inv;
    bf16x8 o0 = *(const bf16x8*)(Op + (size_t)r * D_ + t * 8);
    bf16x8 o1 = *(const bf16x8*)(Op + (size_t)(32768 + r) * D_ + t * 8);
    union { bf16 h[8]; uint4 u; } pk;
#pragma unroll
    for (int e = 0; e < 8; ++e)
        pk.h[e] = (bf16)(w0 * (float)o0[e] + w1 * (float)o1[e]);
    int b = bg >> 2, g = bg & 3;
    *(uint4*)(XT + ((size_t)b * N_ + n) * C_ + g * D_ + t * 8) = pk.u;
}

// ---------- kernel 5: output projection, 128x64 tile ----------
__global__ __launch_bounds__(256) void oproj_kernel(const bf16* __restrict__ Ob,
                                                    const bf16* __restrict__ WB,
                                                    const float* __restrict__ bo,
                                                    const float* __restrict__ x,
                                                    float* __restrict__ out) {
    __shared__ char smem[24576];
    const int tid = threadIdx.x;
    const int w = tid >> 6, l = tid & 63;
    const int lr = l & 15, lg = l >> 4;
    const int wr = w >> 1, wc = w & 1;
    const bf16* W = WB + (size_t)3 * (C_ * C_);
    const int r0 = blockIdx.x * 128, o0 = blockIdx.y * 64;

    const char* srcA[2]; int dA[2];
#pragma unroll
    for (int i = 0; i < 2; ++i) {
        int CL = tid + 256 * i, row = CL >> 2, c = CL & 3;
        srcA[i] = (const char*)(Ob + (size_t)(r0 + row) * C_) + SWZ(row, c);
        dA[i] = CL << 4;
    }
    const char* srcB; int dB;
    {
        int CL = tid, row = CL >> 2, c = CL & 3;
        srcB = (const char*)(W + (size_t)(o0 + row) * C_) + SWZ(row, c);
        dB = 8192 + (CL << 4);
    }

    f32x4 z = {0.f, 0.f, 0.f, 0.f};
    f32x4 acc[4][2];
#pragma unroll
    for (int m = 0; m < 4; ++m) { acc[m][0] = z; acc[m][1] = z; }

    auto STAGE = [&](int buf, int kt) {
        char* base = smem + buf * 12288;
        int kb = kt * 64;
#pragma unroll
        for (int i = 0; i < 2; ++i) gload16(srcA[i] + kb, base + dA[i]);
        gload16(srcB + kb, base + dB);
    };

    STAGE(0, 0);
    __syncthreads();
#pragma unroll 4
    for (int t = 0; t < 16; ++t) {
        int cur = t & 1;
        if (t < 15) STAGE(cur ^ 1, t + 1);
        char* Ab = smem + cur * 12288;
        char* Bb = Ab + 8192;
        bf16x8 af[4], bg_[2];
#pragma unroll
        for (int m = 0; m < 4; ++m) {
            int row = wr * 64 + m * 16 + lr;
            af[m] = *(const bf16x8*)(Ab + row * 64 + SWZ(row, lg));
        }
#pragma unroll
        for (int n = 0; n < 2; ++n) {
            int row = wc * 32 + n * 16 + lr;
            bg_[n] = *(const bf16x8*)(Bb + row * 64 + SWZ(row, lg));
        }
#pragma unroll
        for (int m = 0; m < 4; ++m)
#pragma unroll
            for (int n = 0; n < 2; ++n)
                acc[m][n] = MFMA(af[m], bg_[n], acc[m][n], 0, 0, 0);
        __syncthreads();
    }

#pragma unroll
    for (int n = 0; n < 2; ++n) {
        int o = o0 + wc * 32 + n * 16 + lr;
        float bs = bo[o];
#pragma unroll
        for (int m = 0; m < 4; ++m) {
            int row = r0 + wr * 64 + m * 16 + lg * 4;
            int b = row >> 12, nn = row & (N_ - 1);
            size_t base = ((size_t)b * C_ + o) * N_ + nn;
            float4 xv = *(const float4*)(x + base);
            float4 ov;
            ov.x = acc[m][n][0] + bs + xv.x;
            ov.y = acc[m][n][1] + bs + xv.y;
            ov.z = acc[m][n][2] + bs + xv.z;
            ov.w = acc[m][n][3] + bs + xv.w;
            *(float4*)(out + base) = ov;
        }
    }
}

extern "C" void kernel_launch(void* const* d_in, const int* in_sizes, int n_in,
                              void* d_out, int out_size, void* d_ws, size_t ws_size,
                              hipStream_t stream) {
    const float* x  = (const float*)d_in[0];
    const float* Wq = (const float*)d_in[1];
    const float* bq = (const float*)d_in[2];
    const float* Wk = (const float*)d_in[3];
    const float* bk = (const float*)d_in[4];
    const float* Wv = (const float*)d_in[5];
    const float* bv = (const float*)d_in[6];
    const float* Wo = (const float*)d_in[7];
    const float* bo = (const float*)d_in[8];

    char* ws = (char*)d_ws;
    bf16* Q   = (bf16*)(ws + OFF_Q);
    bf16* K   = (bf16*)(ws + OFF_K);
    bf16* Vt  = (bf16*)(ws + OFF_VT);
    bf16* XT  = (bf16*)(ws + OFF_XT);
    bf16* WB  = (bf16*)(ws + OFF_WB);
    bf16* Op  = (bf16*)(ws + OFF_OP);
    float* ML = (float*)(ws + OFF_ML);
    float* out = (float*)d_out;

    hipLaunchKernelGGL(wcvt_kernel, dim3(256, 4), dim3(256), 0, stream, Wq, Wk, Wv, Wo, WB);
    hipLaunchKernelGGL(xt_kernel, dim3(64, 8, 2), dim3(256), 0, stream, x, XT);
    hipLaunchKernelGGL(qkv_kernel, dim3(64, 4, 3), dim3(256), 0, stream,
                       XT, WB, bq, bk, bv, Q, K, Vt);
    if (ws_size >= (size_t)WS_NEED_SPLIT) {
        hipLaunchKernelGGL(attn_kernel<2>, dim3(256), dim3(512), 0, stream,
                           Q, K, Vt, XT, Op, ML);
        hipLaunchKernelGGL(merge_kernel, dim3(2048), dim3(256), 0, stream, Op, ML, XT);
    } else {
        hipLaunchKernelGGL(attn_kernel<1>, dim3(128), dim3(512), 0, stream,
                           Q, K, Vt, XT, Op, ML);
    }
    hipLaunchKernelGGL(oproj_kernel, dim3(64, 8), dim3(256), 0, stream, XT, WB, bo, x, out);
}

// Round 16
// 133.728 us; speedup vs baseline: 2.1733x; 1.7788x over previous
//
#include <hip/hip_runtime.h>
#include <hip/hip_bf16.h>
#include <stdint.h>

#define B_ 2
#define C_ 512
#define G_ 4
#define D_ 128
#define N_ 4096

typedef __bf16 bf16;
typedef __bf16 bf16x8 __attribute__((ext_vector_type(8)));
typedef float  f32x4  __attribute__((ext_vector_type(4)));
typedef float  f32x16 __attribute__((ext_vector_type(16)));

#define MFMA   __builtin_amdgcn_mfma_f32_16x16x32_bf16
#define MFMA32 __builtin_amdgcn_mfma_f32_32x32x16_bf16

// LDS chunk swizzle for GEMMs: physical chunk = logical chunk ^ ((row>>1)&3)
#define SWZ(row, c) ((((c) ^ (((row) >> 1) & 3)) << 4))

// ---- workspace layout (bytes) ----
#define OFF_Q   (0u)           // [B*G][N][D] bf16 (pre-scaled by SC*log2e)
#define OFF_K   (8388608u)     // [B*G][N][D] bf16
#define OFF_VT  (16777216u)    // [B*G][D][N] bf16
#define OFF_XT  (25165824u)    // [B*N][C] bf16 (xT input; later attn O)
#define OFF_WB  (33554432u)    // 4 x [512][512] bf16
#define OFF_OP  (35651584u)    // bf16 [2][8][4096][128] partial O
#define OFF_ML  (52428800u)    // float2 [2][8][4096] running (m,l)
#define WS_NEED_SPLIT (52953088u)

__device__ inline unsigned pk2(float a, float b) {
    union { bf16 h[2]; unsigned u; } t;
    t.h[0] = (bf16)a; t.h[1] = (bf16)b;
    return t.u;
}
__device__ inline void pl32(unsigned &a, unsigned &b) {
    asm volatile("v_permlane32_swap_b32 %0, %1" : "+v"(a), "+v"(b));
}
__device__ inline void gload16(const char* src, char* lds) {
    __builtin_amdgcn_global_load_lds(
        (const __attribute__((address_space(1))) unsigned*)src,
        (__attribute__((address_space(3))) unsigned*)lds, 16, 0, 0);
}
__device__ inline float max3f(float a, float b, float c) {
    return fmaxf(fmaxf(a, b), c);   // clang fuses to v_max3_f32
}

// ---------- kernel 1: weights fp32 -> bf16 ----------
__global__ __launch_bounds__(256) void wcvt_kernel(const float* __restrict__ Wq,
                                                   const float* __restrict__ Wk,
                                                   const float* __restrict__ Wv,
                                                   const float* __restrict__ Wo,
                                                   bf16* __restrict__ out) {
    int m = blockIdx.y;
    const float* W = (m == 0) ? Wq : (m == 1) ? Wk : (m == 2) ? Wv : Wo;
    int i = (blockIdx.x * 256 + threadIdx.x) * 4;
    float4 v = *(const float4*)(W + i);
    union { bf16 h[4]; uint2 u; } pk;
    pk.h[0] = (bf16)v.x; pk.h[1] = (bf16)v.y; pk.h[2] = (bf16)v.z; pk.h[3] = (bf16)v.w;
    *(uint2*)(out + (size_t)m * (C_ * C_) + i) = pk.u;
}

// ---------- kernel 2: x [b][c][n] f32 -> xT [b*n][c] bf16 ----------
__global__ __launch_bounds__(256) void xt_kernel(const float* __restrict__ x,
                                                 bf16* __restrict__ xT) {
    __shared__ bf16 t[64 * 80];
    int n0 = blockIdx.x * 64, c0 = blockIdx.y * 64, b = blockIdx.z;
    const float* xp = x + (size_t)b * C_ * N_;
#pragma unroll
    for (int i = 0; i < 16; ++i) {
        int idx = threadIdx.x + 256 * i;
        int cl = idx >> 6, nl = idx & 63;
        float v = xp[(size_t)(c0 + cl) * N_ + n0 + nl];
        t[nl * 80 + cl] = (bf16)v;
    }
    __syncthreads();
    bf16* xt = xT + ((size_t)b * N_ + n0) * C_ + c0;
#pragma unroll
    for (int i = 0; i < 2; ++i) {
        int id = threadIdx.x + 256 * i;
        int nl = id >> 3, c8 = (id & 7) * 8;
        *(uint4*)(xt + (size_t)nl * C_ + c8) = *(const uint4*)(t + nl * 80 + c8);
    }
}

// ---------- kernel 3: fused QKV projection, 128x128 tile ----------
__global__ __launch_bounds__(256) void qkv_kernel(const bf16* __restrict__ xT,
                                                  const bf16* __restrict__ WB,
                                                  const float* __restrict__ bq,
                                                  const float* __restrict__ bk,
                                                  const float* __restrict__ bv,
                                                  bf16* __restrict__ Q,
                                                  bf16* __restrict__ K,
                                                  bf16* __restrict__ Vt) {
    __shared__ char smem[32768];
    const int tid = threadIdx.x;
    const int w = tid >> 6, l = tid & 63;
    const int lr = l & 15, lg = l >> 4;
    const int wr = w >> 1, wc = w & 1;
    const int mat = blockIdx.z;
    const bf16* A = xT;
    const bf16* W = WB + (size_t)mat * (C_ * C_);
    const float* bias = (mat == 0) ? bq : (mat == 1) ? bk : bv;
    const int r0 = blockIdx.x * 128, o0 = blockIdx.y * 128;
    const float QSCALE = 0.08838834764831845f * 1.4426950408889634f;

    const char* srcA[2]; const char* srcB[2]; int dA[2], dB[2];
#pragma unroll
    for (int i = 0; i < 2; ++i) {
        int CL = tid + 256 * i, row = CL >> 2, c = CL & 3;
        srcA[i] = (const char*)(A + (size_t)(r0 + row) * C_) + SWZ(row, c);
        srcB[i] = (const char*)(W + (size_t)(o0 + row) * C_) + SWZ(row, c);
        dA[i] = CL << 4;
        dB[i] = 8192 + (CL << 4);
    }

    f32x4 z = {0.f, 0.f, 0.f, 0.f};
    f32x4 acc[4][4];
#pragma unroll
    for (int m = 0; m < 4; ++m)
#pragma unroll
        for (int n = 0; n < 4; ++n) acc[m][n] = z;

    auto STAGE = [&](int buf, int kt) {
        char* base = smem + buf * 16384;
        int kb = kt * 64;
#pragma unroll
        for (int i = 0; i < 2; ++i) {
            gload16(srcA[i] + kb, base + dA[i]);
            gload16(srcB[i] + kb, base + dB[i]);
        }
    };

    STAGE(0, 0);
    __syncthreads();
#pragma unroll 4
    for (int t = 0; t < 16; ++t) {
        int cur = t & 1;
        if (t < 15) STAGE(cur ^ 1, t + 1);
        char* Ab = smem + cur * 16384;
        char* Bb = Ab + 8192;
        bf16x8 af[4], bg_[4];
#pragma unroll
        for (int m = 0; m < 4; ++m) {
            int row = wr * 64 + m * 16 + lr;
            af[m] = *(const bf16x8*)(Ab + row * 64 + SWZ(row, lg));
        }
#pragma unroll
        for (int n = 0; n < 4; ++n) {
            int row = wc * 64 + n * 16 + lr;
            bg_[n] = *(const bf16x8*)(Bb + row * 64 + SWZ(row, lg));
        }
#pragma unroll
        for (int m = 0; m < 4; ++m)
#pragma unroll
            for (int n = 0; n < 4; ++n)
                acc[m][n] = MFMA(af[m], bg_[n], acc[m][n], 0, 0, 0);
        __syncthreads();
    }

#pragma unroll
    for (int n = 0; n < 4; ++n) {
        int o = o0 + wc * 64 + n * 16 + lr;
        float bs = bias[o];
        int g = o >> 7, d = o & 127;
#pragma unroll
        for (int m = 0; m < 4; ++m) {
            int row = r0 + wr * 64 + m * 16 + lg * 4;
            int b = row >> 12, nn = row & (N_ - 1);
            if (mat == 0) {
#pragma unroll
                for (int j = 0; j < 4; ++j)
                    Q[((size_t)(b * G_ + g) * N_ + nn + j) * D_ + d] =
                        (bf16)((acc[m][n][j] + bs) * QSCALE);
            } else if (mat == 1) {
#pragma unroll
                for (int j = 0; j < 4; ++j)
                    K[((size_t)(b * G_ + g) * N_ + nn + j) * D_ + d] =
                        (bf16)(acc[m][n][j] + bs);
            } else {
                union { bf16 h[4]; uint2 u; } pk;
#pragma unroll
                for (int j = 0; j < 4; ++j) pk.h[j] = (bf16)(acc[m][n][j] + bs);
                *(uint2*)(Vt + ((size_t)(b * G_ + g) * D_ + d) * N_ + nn) = pk.u;
            }
        }
    }
}

// ---------- kernel 4: flash attention, 32x32 swapped-QK, KVB=64, 8-wave blocks ----------
// 8 waves x 32 q = 256 q/block, grid 256 -> 1 block/CU (best measured config, r13).
template<int SPLITS>
__global__ __launch_bounds__(512, 2) void attn_kernel(const bf16* __restrict__ Q,
                                                      const bf16* __restrict__ K,
                                                      const bf16* __restrict__ Vt,
                                                      bf16* __restrict__ XT,
                                                      bf16* __restrict__ Op,
                                                      float* __restrict__ ML) {
    __shared__ char smem[65536];
    const int tid = threadIdx.x;
    const int w = tid >> 6, l = tid & 63;
    const int l31 = l & 31, h = l >> 5;

    // 1-D grid: 256 (SPLITS=2) or 128 (SPLITS=1); xcd = L%8 -> head
    const int L = blockIdx.x;
    const int bg = L & 7;
    const int ix = L >> 3;
    const int sp = (SPLITS > 1) ? (ix >> 4) : 0;
    const int qb = (SPLITS > 1) ? (ix & 15) : ix;

    const bf16* Qh = Q + (size_t)bg * N_ * D_;
    const char* Kh = (const char*)(K + (size_t)bg * N_ * D_);
    const char* Vh = (const char*)(Vt + (size_t)bg * D_ * N_);
    const int q0 = qb * 256 + w * 32;
    const int kv0 = sp * (N_ / SPLITS);
    const int NT = N_ / SPLITS / 64;

    // staging offsets: 8 waves x 2 chunks each for K (16 x 1KB) and V
    int offK[2], offV[2];
#pragma unroll
    for (int j = 0; j < 2; ++j) {
        int CL = (w * 2 + j) * 64 + l;
        int row = CL >> 4;
        int cp = (CL & 15) ^ (row & 15);
        offK[j] = row * 256 + cp * 16;
        int dv = 2 * row + (cp >> 3), k8 = cp & 7;
        offV[j] = dv * (N_ * 2) + k8 * 16;
    }

    bf16x8 aq[8];
#pragma unroll
    for (int kb = 0; kb < 8; ++kb)
        aq[kb] = *(const bf16x8*)(Qh + (size_t)(q0 + l31) * D_ + kb * 16 + h * 8);

    bf16 one_ = (bf16)1.0f;
    bf16x8 ones = {one_, one_, one_, one_, one_, one_, one_, one_};

    f32x16 oacc[4], lacc;
#pragma unroll
    for (int dt = 0; dt < 4; ++dt)
#pragma unroll
        for (int r = 0; r < 16; ++r) oacc[dt][r] = 0.f;
#pragma unroll
    for (int r = 0; r < 16; ++r) lacc[r] = 0.f;
    float mrun = -1e30f;
    const float THR = 5.0f;

    auto STAGE = [&](int buf, int kv) {
        const char* pk = Kh + (size_t)kv * 256;
        const char* pv = Vh + (size_t)kv * 2;
        char* kb = smem + buf * 32768 + w * 2048;
        char* vb = smem + buf * 32768 + 16384 + w * 2048;
#pragma unroll
        for (int j = 0; j < 2; ++j) gload16(pk + offK[j], kb + j * 1024);
#pragma unroll
        for (int j = 0; j < 2; ++j) gload16(pv + offV[j], vb + j * 1024);
    };

    STAGE(0, kv0);

    for (int t = 0; t < NT; ++t) {
        int cur = t & 1;
        __builtin_amdgcn_s_barrier();
        if (t + 1 < NT) {
            STAGE(cur ^ 1, kv0 + (t + 1) * 64);
            asm volatile("s_waitcnt vmcnt(4)" ::: "memory");  // drain tile t, keep t+1
        } else {
            asm volatile("s_waitcnt vmcnt(0)" ::: "memory");
        }
        __builtin_amdgcn_sched_barrier(0);
        __builtin_amdgcn_s_barrier();
        char* Kb = smem + cur * 32768;
        char* Vb = smem + cur * 32768 + 16384;

        // ---- S^T = K Q^T ----
        f32x16 s0, s1;
#pragma unroll
        for (int r = 0; r < 16; ++r) { s0[r] = 0.f; s1[r] = 0.f; }
        __builtin_amdgcn_s_setprio(1);
#pragma unroll
        for (int kb = 0; kb < 8; ++kb) {
            int ch = (((kb << 1) | h) ^ (l31 & 15)) << 4;
            bf16x8 kf0 = *(const bf16x8*)(Kb + (size_t)l31 * 256 + ch);
            s0 = MFMA32(kf0, aq[kb], s0, 0, 0, 0);
            bf16x8 kf1 = *(const bf16x8*)(Kb + (size_t)(32 + l31) * 256 + ch);
            s1 = MFMA32(kf1, aq[kb], s1, 0, 0, 0);
        }
        __builtin_amdgcn_s_setprio(0);

        // ---- tile max via max3 tree (lane owns q = l31) ----
        float x0 = max3f(s0[0],  s0[1],  s0[2]);
        float x1 = max3f(s0[3],  s0[4],  s0[5]);
        float x2 = max3f(s0[6],  s0[7],  s0[8]);
        float x3 = max3f(s0[9],  s0[10], s0[11]);
        float x4 = max3f(s0[12], s0[13], s0[14]);
        float x5 = max3f(s0[15], s1[0],  s1[1]);
        float x6 = max3f(s1[2],  s1[3],  s1[4]);
        float x7 = max3f(s1[5],  s1[6],  s1[7]);
        float x8 = max3f(s1[8],  s1[9],  s1[10]);
        float x9 = max3f(s1[11], s1[12], s1[13]);
        float xa = fmaxf(s1[14], s1[15]);
        float y0 = max3f(x0, x1, x2);
        float y1 = max3f(x3, x4, x5);
        float y2 = max3f(x6, x7, x8);
        float y3 = fmaxf(x9, xa);
        float mt = fmaxf(max3f(y0, y1, y2), y3);
        mt = fmaxf(mt, __shfl_xor(mt, 32));

        if (__any(mt > mrun + THR)) {
            float mn = fmaxf(mrun, mt);
            float corr = __builtin_amdgcn_exp2f(mrun - mn);
            mrun = mn;
#pragma unroll
            for (int r = 0; r < 16; ++r) {
                int qr = (r & 3) + 8 * (r >> 2) + 4 * h;
                float cr = __shfl(corr, qr);
                lacc[r] *= cr;
#pragma unroll
                for (int dt = 0; dt < 4; ++dt) oacc[dt][r] *= cr;
            }
        }

#pragma unroll
        for (int r = 0; r < 16; ++r) {
            s0[r] = __builtin_amdgcn_exp2f(s0[r] - mrun);
            s1[r] = __builtin_amdgcn_exp2f(s1[r] - mrun);
        }

        // ---- P -> bf16 PV A-fragments via pack + permlane32_swap ----
        bf16x8 pa0, pa1, pa2, pa3;
        {
            unsigned x0_ = pk2(s0[0], s0[1]),  y0_ = pk2(s0[4], s0[5]);  pl32(x0_, y0_);
            unsigned x1_ = pk2(s0[2], s0[3]),  y1_ = pk2(s0[6], s0[7]);  pl32(x1_, y1_);
            pa0 = __builtin_bit_cast(bf16x8, (uint4){x0_, x1_, y0_, y1_});
            unsigned x2_ = pk2(s0[8], s0[9]),  y2_ = pk2(s0[12], s0[13]); pl32(x2_, y2_);
            unsigned x3_ = pk2(s0[10], s0[11]), y3_ = pk2(s0[14], s0[15]); pl32(x3_, y3_);
            pa1 = __builtin_bit_cast(bf16x8, (uint4){x2_, x3_, y2_, y3_});
            unsigned x4_ = pk2(s1[0], s1[1]),  y4_ = pk2(s1[4], s1[5]);  pl32(x4_, y4_);
            unsigned x5_ = pk2(s1[2], s1[3]),  y5_ = pk2(s1[6], s1[7]);  pl32(x5_, y5_);
            pa2 = __builtin_bit_cast(bf16x8, (uint4){x4_, x5_, y4_, y5_});
            unsigned x6_ = pk2(s1[8], s1[9]),  y6_ = pk2(s1[12], s1[13]); pl32(x6_, y6_);
            unsigned x7_ = pk2(s1[10], s1[11]), y7_ = pk2(s1[14], s1[15]); pl32(x7_, y7_);
            pa3 = __builtin_bit_cast(bf16x8, (uint4){x6_, x7_, y6_, y7_});
        }

        // ---- O += P V ; l += P 1 (row-sum on the MFMA pipe) ----
        __builtin_amdgcn_s_setprio(1);
#pragma unroll
        for (int sl = 0; sl < 4; ++sl) {
            bf16x8 pa = (sl == 0) ? pa0 : (sl == 1) ? pa1 : (sl == 2) ? pa2 : pa3;
#pragma unroll
            for (int dt = 0; dt < 4; ++dt) {
                int row = dt * 16 + (l31 >> 1);
                int ch = ((((l31 & 1) << 3) + (sl << 1) + h) ^ (l31 >> 1)) << 4;
                bf16x8 vf = *(const bf16x8*)(Vb + (size_t)row * 256 + ch);
                oacc[dt] = MFMA32(pa, vf, oacc[dt], 0, 0, 0);
            }
            lacc = MFMA32(pa, ones, lacc, 0, 0, 0);
        }
        __builtin_amdgcn_s_setprio(0);
    }

    // ---- epilogue ----
    if (SPLITS > 1) {
        float2* mlp = (float2*)ML + ((size_t)sp * 8 + bg) * N_ + q0;
#pragma unroll
        for (int r = 0; r < 16; ++r) {
            int qr = (r & 3) + 8 * (r >> 2) + 4 * h;
            float mv = __shfl(mrun, qr);
            if (l31 == 0) {
                float2 v; v.x = mv; v.y = lacc[r];
                mlp[qr] = v;
            }
        }
        bf16* op = Op + (((size_t)sp * 8 + bg) * N_ + q0) * D_;
#pragma unroll
        for (int dt = 0; dt < 4; ++dt)
#pragma unroll
            for (int r = 0; r < 16; ++r) {
                int qr = (r & 3) + 8 * (r >> 2) + 4 * h;
                op[(size_t)qr * D_ + dt * 32 + l31] = (bf16)oacc[dt][r];
            }
    } else {
        int b = bg >> 2, g = bg & 3;
#pragma unroll
        for (int r = 0; r < 16; ++r) {
            int qr = (r & 3) + 8 * (r >> 2) + 4 * h;
            float iv = 1.f / lacc[r];
#pragma unroll
            for (int dt = 0; dt < 4; ++dt)
                XT[((size_t)b * N_ + q0 + qr) * C_ + g * D_ + dt * 32 + l31] =
                    (bf16)(oacc[dt][r] * iv);
        }
    }
}

// ---------- kernel 4b: merge the 2 KV-split partials ----------
__global__ __launch_bounds__(256) void merge_kernel(const bf16* __restrict__ Op,
                                                    const float* __restrict__ ML,
                                                    bf16* __restrict__ XT) {
    int t = threadIdx.x & 15, rl = threadIdx.x >> 4;
    int r = blockIdx.x * 16 + rl;
    int bg = r >> 12, n = r & (N_ - 1);
    const float2* mlp = (const float2*)ML;
    float2 ml0 = mlp[r], ml1 = mlp[32768 + r];
    float mm = fmaxf(ml0.x, ml1.x);
    float w0 = __builtin_amdgcn_exp2f(ml0.x - mm);
    float w1 = __builtin_amdgcn_exp2f(ml1.x - mm);
    float inv = 1.f / (w0 * ml0.y + w1 * ml1.y);
    w0 *= inv; w1 *= inv;
    bf16x8 o0 = *(const bf16x8*)(Op + (size_t)r * D_ + t * 8);
    bf16x8 o1 = *(const bf16x8*)(Op + (size_t)(32768 + r) * D_ + t * 8);
    union { bf16 h[8]; uint4 u; } pk;
#pragma unroll
    for (int e = 0; e < 8; ++e)
        pk.h[e] = (bf16)(w0 * (float)o0[e] + w1 * (float)o1[e]);
    int b = bg >> 2, g = bg & 3;
    *(uint4*)(XT + ((size_t)b * N_ + n) * C_ + g * D_ + t * 8) = pk.u;
}

// ---------- kernel 5: output projection, 128x64 tile ----------
__global__ __launch_bounds__(256) void oproj_kernel(const bf16* __restrict__ Ob,
                                                    const bf16* __restrict__ WB,
                                                    const float* __restrict__ bo,
                                                    const float* __restrict__ x,
                                                    float* __restrict__ out) {
    __shared__ char smem[24576];
    const int tid = threadIdx.x;
    const int w = tid >> 6, l = tid & 63;
    const int lr = l & 15, lg = l >> 4;
    const int wr = w >> 1, wc = w & 1;
    const bf16* W = WB + (size_t)3 * (C_ * C_);
    const int r0 = blockIdx.x * 128, o0 = blockIdx.y * 64;

    const char* srcA[2]; int dA[2];
#pragma unroll
    for (int i = 0; i < 2; ++i) {
        int CL = tid + 256 * i, row = CL >> 2, c = CL & 3;
        srcA[i] = (const char*)(Ob + (size_t)(r0 + row) * C_) + SWZ(row, c);
        dA[i] = CL << 4;
    }
    const char* srcB; int dB;
    {
        int CL = tid, row = CL >> 2, c = CL & 3;
        srcB = (const char*)(W + (size_t)(o0 + row) * C_) + SWZ(row, c);
        dB = 8192 + (CL << 4);
    }

    f32x4 z = {0.f, 0.f, 0.f, 0.f};
    f32x4 acc[4][2];
#pragma unroll
    for (int m = 0; m < 4; ++m) { acc[m][0] = z; acc[m][1] = z; }

    auto STAGE = [&](int buf, int kt) {
        char* base = smem + buf * 12288;
        int kb = kt * 64;
#pragma unroll
        for (int i = 0; i < 2; ++i) gload16(srcA[i] + kb, base + dA[i]);
        gload16(srcB + kb, base + dB);
    };

    STAGE(0, 0);
    __syncthreads();
#pragma unroll 4
    for (int t = 0; t < 16; ++t) {
        int cur = t & 1;
        if (t < 15) STAGE(cur ^ 1, t + 1);
        char* Ab = smem + cur * 12288;
        char* Bb = Ab + 8192;
        bf16x8 af[4], bg_[2];
#pragma unroll
        for (int m = 0; m < 4; ++m) {
            int row = wr * 64 + m * 16 + lr;
            af[m] = *(const bf16x8*)(Ab + row * 64 + SWZ(row, lg));
        }
#pragma unroll
        for (int n = 0; n < 2; ++n) {
            int row = wc * 32 + n * 16 + lr;
            bg_[n] = *(const bf16x8*)(Bb + row * 64 + SWZ(row, lg));
        }
#pragma unroll
        for (int m = 0; m < 4; ++m)
#pragma unroll
            for (int n = 0; n < 2; ++n)
                acc[m][n] = MFMA(af[m], bg_[n], acc[m][n], 0, 0, 0);
        __syncthreads();
    }

#pragma unroll
    for (int n = 0; n < 2; ++n) {
        int o = o0 + wc * 32 + n * 16 + lr;
        float bs = bo[o];
#pragma unroll
        for (int m = 0; m < 4; ++m) {
            int row = r0 + wr * 64 + m * 16 + lg * 4;
            int b = row >> 12, nn = row & (N_ - 1);
            size_t base = ((size_t)b * C_ + o) * N_ + nn;
            float4 xv = *(const float4*)(x + base);
            float4 ov;
            ov.x = acc[m][n][0] + bs + xv.x;
            ov.y = acc[m][n][1] + bs + xv.y;
            ov.z = acc[m][n][2] + bs + xv.z;
            ov.w = acc[m][n][3] + bs + xv.w;
            *(float4*)(out + base) = ov;
        }
    }
}

extern "C" void kernel_launch(void* const* d_in, const int* in_sizes, int n_in,
                              void* d_out, int out_size, void* d_ws, size_t ws_size,
                              hipStream_t stream) {
    const float* x  = (const float*)d_in[0];
    const float* Wq = (const float*)d_in[1];
    const float* bq = (const float*)d_in[2];
    const float* Wk = (const float*)d_in[3];
    const float* bk = (const float*)d_in[4];
    const float* Wv = (const float*)d_in[5];
    const float* bv = (const float*)d_in[6];
    const float* Wo = (const float*)d_in[7];
    const float* bo = (const float*)d_in[8];

    char* ws = (char*)d_ws;
    bf16* Q   = (bf16*)(ws + OFF_Q);
    bf16* K   = (bf16*)(ws + OFF_K);
    bf16* Vt  = (bf16*)(ws + OFF_VT);
    bf16* XT  = (bf16*)(ws + OFF_XT);
    bf16* WB  = (bf16*)(ws + OFF_WB);
    bf16* Op  = (bf16*)(ws + OFF_OP);
    float* ML = (float*)(ws + OFF_ML);
    float* out = (float*)d_out;

    hipLaunchKernelGGL(wcvt_kernel, dim3(256, 4), dim3(256), 0, stream, Wq, Wk, Wv, Wo, WB);
    hipLaunchKernelGGL(xt_kernel, dim3(64, 8, 2), dim3(256), 0, stream, x, XT);
    hipLaunchKernelGGL(qkv_kernel, dim3(64, 4, 3), dim3(256), 0, stream,
                       XT, WB, bq, bk, bv, Q, K, Vt);
    if (ws_size >= (size_t)WS_NEED_SPLIT) {
        hipLaunchKernelGGL(attn_kernel<2>, dim3(256), dim3(512), 0, stream,
                           Q, K, Vt, XT, Op, ML);
        hipLaunchKernelGGL(merge_kernel, dim3(2048), dim3(256), 0, stream, Op, ML, XT);
    } else {
        hipLaunchKernelGGL(attn_kernel<1>, dim3(128), dim3(512), 0, stream,
                           Q, K, Vt, XT, Op, ML);
    }
    hipLaunchKernelGGL(oproj_kernel, dim3(64, 8), dim3(256), 0, stream, XT, WB, bo, x, out);
}

// Round 17
// 131.936 us; speedup vs baseline: 2.2028x; 1.0136x over previous
//
#include <hip/hip_runtime.h>
#include <hip/hip_bf16.h>
#include <stdint.h>

#define B_ 2
#define C_ 512
#define G_ 4
#define D_ 128
#define N_ 4096

typedef __bf16 bf16;
typedef __bf16 bf16x8 __attribute__((ext_vector_type(8)));
typedef float  f32x4  __attribute__((ext_vector_type(4)));
typedef float  f32x16 __attribute__((ext_vector_type(16)));

#define MFMA   __builtin_amdgcn_mfma_f32_16x16x32_bf16
#define MFMA32 __builtin_amdgcn_mfma_f32_32x32x16_bf16

// LDS chunk swizzle for GEMMs: physical chunk = logical chunk ^ ((row>>1)&3)
#define SWZ(row, c) ((((c) ^ (((row) >> 1) & 3)) << 4))

// ---- workspace layout (bytes) ----
#define OFF_Q   (0u)           // [B*G][N][D] bf16 (pre-scaled by SC*log2e)
#define OFF_K   (8388608u)     // [B*G][N][D] bf16
#define OFF_VT  (16777216u)    // [B*G][D][N] bf16
#define OFF_XT  (25165824u)    // [B*N][C] bf16 (xT input; attn<1> O)
#define OFF_WB  (33554432u)    // 4 x [512][512] bf16
#define OFF_OP  (35651584u)    // bf16 [2][8][4096][128] partial O
#define OFF_ML  (52428800u)    // float2 [2][8][4096] running (m,l)
#define WS_NEED_SPLIT (52953088u)

__device__ inline unsigned pk2(float a, float b) {
    union { bf16 h[2]; unsigned u; } t;
    t.h[0] = (bf16)a; t.h[1] = (bf16)b;
    return t.u;
}
__device__ inline void pl32(unsigned &a, unsigned &b) {
    asm volatile("v_permlane32_swap_b32 %0, %1" : "+v"(a), "+v"(b));
}
__device__ inline void gload16(const char* src, char* lds) {
    __builtin_amdgcn_global_load_lds(
        (const __attribute__((address_space(1))) unsigned*)src,
        (__attribute__((address_space(3))) unsigned*)lds, 16, 0, 0);
}
__device__ inline float max3f(float a, float b, float c) {
    return fmaxf(fmaxf(a, b), c);   // clang fuses to v_max3_f32
}

// ---------- kernel 1: weights fp32 -> bf16 ----------
__global__ __launch_bounds__(256) void wcvt_kernel(const float* __restrict__ Wq,
                                                   const float* __restrict__ Wk,
                                                   const float* __restrict__ Wv,
                                                   const float* __restrict__ Wo,
                                                   bf16* __restrict__ out) {
    int m = blockIdx.y;
    const float* W = (m == 0) ? Wq : (m == 1) ? Wk : (m == 2) ? Wv : Wo;
    int i = (blockIdx.x * 256 + threadIdx.x) * 4;
    float4 v = *(const float4*)(W + i);
    union { bf16 h[4]; uint2 u; } pk;
    pk.h[0] = (bf16)v.x; pk.h[1] = (bf16)v.y; pk.h[2] = (bf16)v.z; pk.h[3] = (bf16)v.w;
    *(uint2*)(out + (size_t)m * (C_ * C_) + i) = pk.u;
}

// ---------- kernel 2: x [b][c][n] f32 -> xT [b*n][c] bf16 ----------
__global__ __launch_bounds__(256) void xt_kernel(const float* __restrict__ x,
                                                 bf16* __restrict__ xT) {
    __shared__ bf16 t[64 * 80];
    int n0 = blockIdx.x * 64, c0 = blockIdx.y * 64, b = blockIdx.z;
    const float* xp = x + (size_t)b * C_ * N_;
#pragma unroll
    for (int i = 0; i < 16; ++i) {
        int idx = threadIdx.x + 256 * i;
        int cl = idx >> 6, nl = idx & 63;
        float v = xp[(size_t)(c0 + cl) * N_ + n0 + nl];
        t[nl * 80 + cl] = (bf16)v;
    }
    __syncthreads();
    bf16* xt = xT + ((size_t)b * N_ + n0) * C_ + c0;
#pragma unroll
    for (int i = 0; i < 2; ++i) {
        int id = threadIdx.x + 256 * i;
        int nl = id >> 3, c8 = (id & 7) * 8;
        *(uint4*)(xt + (size_t)nl * C_ + c8) = *(const uint4*)(t + nl * 80 + c8);
    }
}

// ---------- kernel 3: fused QKV projection, 128x128 tile ----------
__global__ __launch_bounds__(256) void qkv_kernel(const bf16* __restrict__ xT,
                                                  const bf16* __restrict__ WB,
                                                  const float* __restrict__ bq,
                                                  const float* __restrict__ bk,
                                                  const float* __restrict__ bv,
                                                  bf16* __restrict__ Q,
                                                  bf16* __restrict__ K,
                                                  bf16* __restrict__ Vt) {
    __shared__ char smem[32768];
    const int tid = threadIdx.x;
    const int w = tid >> 6, l = tid & 63;
    const int lr = l & 15, lg = l >> 4;
    const int wr = w >> 1, wc = w & 1;
    const int mat = blockIdx.z;
    const bf16* A = xT;
    const bf16* W = WB + (size_t)mat * (C_ * C_);
    const float* bias = (mat == 0) ? bq : (mat == 1) ? bk : bv;
    const int r0 = blockIdx.x * 128, o0 = blockIdx.y * 128;
    const float QSCALE = 0.08838834764831845f * 1.4426950408889634f;

    const char* srcA[2]; const char* srcB[2]; int dA[2], dB[2];
#pragma unroll
    for (int i = 0; i < 2; ++i) {
        int CL = tid + 256 * i, row = CL >> 2, c = CL & 3;
        srcA[i] = (const char*)(A + (size_t)(r0 + row) * C_) + SWZ(row, c);
        srcB[i] = (const char*)(W + (size_t)(o0 + row) * C_) + SWZ(row, c);
        dA[i] = CL << 4;
        dB[i] = 8192 + (CL << 4);
    }

    f32x4 z = {0.f, 0.f, 0.f, 0.f};
    f32x4 acc[4][4];
#pragma unroll
    for (int m = 0; m < 4; ++m)
#pragma unroll
        for (int n = 0; n < 4; ++n) acc[m][n] = z;

    auto STAGE = [&](int buf, int kt) {
        char* base = smem + buf * 16384;
        int kb = kt * 64;
#pragma unroll
        for (int i = 0; i < 2; ++i) {
            gload16(srcA[i] + kb, base + dA[i]);
            gload16(srcB[i] + kb, base + dB[i]);
        }
    };

    STAGE(0, 0);
    __syncthreads();
#pragma unroll 4
    for (int t = 0; t < 16; ++t) {
        int cur = t & 1;
        if (t < 15) STAGE(cur ^ 1, t + 1);
        char* Ab = smem + cur * 16384;
        char* Bb = Ab + 8192;
        bf16x8 af[4], bg_[4];
#pragma unroll
        for (int m = 0; m < 4; ++m) {
            int row = wr * 64 + m * 16 + lr;
            af[m] = *(const bf16x8*)(Ab + row * 64 + SWZ(row, lg));
        }
#pragma unroll
        for (int n = 0; n < 4; ++n) {
            int row = wc * 64 + n * 16 + lr;
            bg_[n] = *(const bf16x8*)(Bb + row * 64 + SWZ(row, lg));
        }
#pragma unroll
        for (int m = 0; m < 4; ++m)
#pragma unroll
            for (int n = 0; n < 4; ++n)
                acc[m][n] = MFMA(af[m], bg_[n], acc[m][n], 0, 0, 0);
        __syncthreads();
    }

#pragma unroll
    for (int n = 0; n < 4; ++n) {
        int o = o0 + wc * 64 + n * 16 + lr;
        float bs = bias[o];
        int g = o >> 7, d = o & 127;
#pragma unroll
        for (int m = 0; m < 4; ++m) {
            int row = r0 + wr * 64 + m * 16 + lg * 4;
            int b = row >> 12, nn = row & (N_ - 1);
            if (mat == 0) {
#pragma unroll
                for (int j = 0; j < 4; ++j)
                    Q[((size_t)(b * G_ + g) * N_ + nn + j) * D_ + d] =
                        (bf16)((acc[m][n][j] + bs) * QSCALE);
            } else if (mat == 1) {
#pragma unroll
                for (int j = 0; j < 4; ++j)
                    K[((size_t)(b * G_ + g) * N_ + nn + j) * D_ + d] =
                        (bf16)(acc[m][n][j] + bs);
            } else {
                union { bf16 h[4]; uint2 u; } pk;
#pragma unroll
                for (int j = 0; j < 4; ++j) pk.h[j] = (bf16)(acc[m][n][j] + bs);
                *(uint2*)(Vt + ((size_t)(b * G_ + g) * D_ + d) * N_ + nn) = pk.u;
            }
        }
    }
}

// ---------- kernel 4: flash attention, 32x32 swapped-QK, KVB=64, 8-wave blocks ----------
// 8 waves x 32 q = 256 q/block, grid 256 -> 1 block/CU (best measured config, r13).
template<int SPLITS>
__global__ __launch_bounds__(512, 2) void attn_kernel(const bf16* __restrict__ Q,
                                                      const bf16* __restrict__ K,
                                                      const bf16* __restrict__ Vt,
                                                      bf16* __restrict__ XT,
                                                      bf16* __restrict__ Op,
                                                      float* __restrict__ ML) {
    __shared__ char smem[65536];
    const int tid = threadIdx.x;
    const int w = tid >> 6, l = tid & 63;
    const int l31 = l & 31, h = l >> 5;

    const int L = blockIdx.x;
    const int bg = L & 7;
    const int ix = L >> 3;
    const int sp = (SPLITS > 1) ? (ix >> 4) : 0;
    const int qb = (SPLITS > 1) ? (ix & 15) : ix;

    const bf16* Qh = Q + (size_t)bg * N_ * D_;
    const char* Kh = (const char*)(K + (size_t)bg * N_ * D_);
    const char* Vh = (const char*)(Vt + (size_t)bg * D_ * N_);
    const int q0 = qb * 256 + w * 32;
    const int kv0 = sp * (N_ / SPLITS);
    const int NT = N_ / SPLITS / 64;

    int offK[2], offV[2];
#pragma unroll
    for (int j = 0; j < 2; ++j) {
        int CL = (w * 2 + j) * 64 + l;
        int row = CL >> 4;
        int cp = (CL & 15) ^ (row & 15);
        offK[j] = row * 256 + cp * 16;
        int dv = 2 * row + (cp >> 3), k8 = cp & 7;
        offV[j] = dv * (N_ * 2) + k8 * 16;
    }

    bf16x8 aq[8];
#pragma unroll
    for (int kb = 0; kb < 8; ++kb)
        aq[kb] = *(const bf16x8*)(Qh + (size_t)(q0 + l31) * D_ + kb * 16 + h * 8);

    bf16 one_ = (bf16)1.0f;
    bf16x8 ones = {one_, one_, one_, one_, one_, one_, one_, one_};

    f32x16 oacc[4], lacc;
#pragma unroll
    for (int dt = 0; dt < 4; ++dt)
#pragma unroll
        for (int r = 0; r < 16; ++r) oacc[dt][r] = 0.f;
#pragma unroll
    for (int r = 0; r < 16; ++r) lacc[r] = 0.f;
    float mrun = -1e30f;
    const float THR = 5.0f;

    auto STAGE = [&](int buf, int kv) {
        const char* pk = Kh + (size_t)kv * 256;
        const char* pv = Vh + (size_t)kv * 2;
        char* kb = smem + buf * 32768 + w * 2048;
        char* vb = smem + buf * 32768 + 16384 + w * 2048;
#pragma unroll
        for (int j = 0; j < 2; ++j) gload16(pk + offK[j], kb + j * 1024);
#pragma unroll
        for (int j = 0; j < 2; ++j) gload16(pv + offV[j], vb + j * 1024);
    };

    STAGE(0, kv0);

    for (int t = 0; t < NT; ++t) {
        int cur = t & 1;
        __builtin_amdgcn_s_barrier();
        if (t + 1 < NT) {
            STAGE(cur ^ 1, kv0 + (t + 1) * 64);
            asm volatile("s_waitcnt vmcnt(4)" ::: "memory");
        } else {
            asm volatile("s_waitcnt vmcnt(0)" ::: "memory");
        }
        __builtin_amdgcn_sched_barrier(0);
        __builtin_amdgcn_s_barrier();
        char* Kb = smem + cur * 32768;
        char* Vb = smem + cur * 32768 + 16384;

        f32x16 s0, s1;
#pragma unroll
        for (int r = 0; r < 16; ++r) { s0[r] = 0.f; s1[r] = 0.f; }
        __builtin_amdgcn_s_setprio(1);
#pragma unroll
        for (int kb = 0; kb < 8; ++kb) {
            int ch = (((kb << 1) | h) ^ (l31 & 15)) << 4;
            bf16x8 kf0 = *(const bf16x8*)(Kb + (size_t)l31 * 256 + ch);
            s0 = MFMA32(kf0, aq[kb], s0, 0, 0, 0);
            bf16x8 kf1 = *(const bf16x8*)(Kb + (size_t)(32 + l31) * 256 + ch);
            s1 = MFMA32(kf1, aq[kb], s1, 0, 0, 0);
        }
        __builtin_amdgcn_s_setprio(0);

        float x0 = max3f(s0[0],  s0[1],  s0[2]);
        float x1 = max3f(s0[3],  s0[4],  s0[5]);
        float x2 = max3f(s0[6],  s0[7],  s0[8]);
        float x3 = max3f(s0[9],  s0[10], s0[11]);
        float x4 = max3f(s0[12], s0[13], s0[14]);
        float x5 = max3f(s0[15], s1[0],  s1[1]);
        float x6 = max3f(s1[2],  s1[3],  s1[4]);
        float x7 = max3f(s1[5],  s1[6],  s1[7]);
        float x8 = max3f(s1[8],  s1[9],  s1[10]);
        float x9 = max3f(s1[11], s1[12], s1[13]);
        float xa = fmaxf(s1[14], s1[15]);
        float y0 = max3f(x0, x1, x2);
        float y1 = max3f(x3, x4, x5);
        float y2 = max3f(x6, x7, x8);
        float y3 = fmaxf(x9, xa);
        float mt = fmaxf(max3f(y0, y1, y2), y3);
        mt = fmaxf(mt, __shfl_xor(mt, 32));

        if (__any(mt > mrun + THR)) {
            float mn = fmaxf(mrun, mt);
            float corr = __builtin_amdgcn_exp2f(mrun - mn);
            mrun = mn;
#pragma unroll
            for (int r = 0; r < 16; ++r) {
                int qr = (r & 3) + 8 * (r >> 2) + 4 * h;
                float cr = __shfl(corr, qr);
                lacc[r] *= cr;
#pragma unroll
                for (int dt = 0; dt < 4; ++dt) oacc[dt][r] *= cr;
            }
        }

#pragma unroll
        for (int r = 0; r < 16; ++r) {
            s0[r] = __builtin_amdgcn_exp2f(s0[r] - mrun);
            s1[r] = __builtin_amdgcn_exp2f(s1[r] - mrun);
        }

        bf16x8 pa0, pa1, pa2, pa3;
        {
            unsigned x0_ = pk2(s0[0], s0[1]),  y0_ = pk2(s0[4], s0[5]);  pl32(x0_, y0_);
            unsigned x1_ = pk2(s0[2], s0[3]),  y1_ = pk2(s0[6], s0[7]);  pl32(x1_, y1_);
            pa0 = __builtin_bit_cast(bf16x8, (uint4){x0_, x1_, y0_, y1_});
            unsigned x2_ = pk2(s0[8], s0[9]),  y2_ = pk2(s0[12], s0[13]); pl32(x2_, y2_);
            unsigned x3_ = pk2(s0[10], s0[11]), y3_ = pk2(s0[14], s0[15]); pl32(x3_, y3_);
            pa1 = __builtin_bit_cast(bf16x8, (uint4){x2_, x3_, y2_, y3_});
            unsigned x4_ = pk2(s1[0], s1[1]),  y4_ = pk2(s1[4], s1[5]);  pl32(x4_, y4_);
            unsigned x5_ = pk2(s1[2], s1[3]),  y5_ = pk2(s1[6], s1[7]);  pl32(x5_, y5_);
            pa2 = __builtin_bit_cast(bf16x8, (uint4){x4_, x5_, y4_, y5_});
            unsigned x6_ = pk2(s1[8], s1[9]),  y6_ = pk2(s1[12], s1[13]); pl32(x6_, y6_);
            unsigned x7_ = pk2(s1[10], s1[11]), y7_ = pk2(s1[14], s1[15]); pl32(x7_, y7_);
            pa3 = __builtin_bit_cast(bf16x8, (uint4){x6_, x7_, y6_, y7_});
        }

        __builtin_amdgcn_s_setprio(1);
#pragma unroll
        for (int sl = 0; sl < 4; ++sl) {
            bf16x8 pa = (sl == 0) ? pa0 : (sl == 1) ? pa1 : (sl == 2) ? pa2 : pa3;
#pragma unroll
            for (int dt = 0; dt < 4; ++dt) {
                int row = dt * 16 + (l31 >> 1);
                int ch = ((((l31 & 1) << 3) + (sl << 1) + h) ^ (l31 >> 1)) << 4;
                bf16x8 vf = *(const bf16x8*)(Vb + (size_t)row * 256 + ch);
                oacc[dt] = MFMA32(pa, vf, oacc[dt], 0, 0, 0);
            }
            lacc = MFMA32(pa, ones, lacc, 0, 0, 0);
        }
        __builtin_amdgcn_s_setprio(0);
    }

    if (SPLITS > 1) {
        float2* mlp = (float2*)ML + ((size_t)sp * 8 + bg) * N_ + q0;
#pragma unroll
        for (int r = 0; r < 16; ++r) {
            int qr = (r & 3) + 8 * (r >> 2) + 4 * h;
            float mv = __shfl(mrun, qr);
            if (l31 == 0) {
                float2 v; v.x = mv; v.y = lacc[r];
                mlp[qr] = v;
            }
        }
        bf16* op = Op + (((size_t)sp * 8 + bg) * N_ + q0) * D_;
#pragma unroll
        for (int dt = 0; dt < 4; ++dt)
#pragma unroll
            for (int r = 0; r < 16; ++r) {
                int qr = (r & 3) + 8 * (r >> 2) + 4 * h;
                op[(size_t)qr * D_ + dt * 32 + l31] = (bf16)oacc[dt][r];
            }
    } else {
        int b = bg >> 2, g = bg & 3;
#pragma unroll
        for (int r = 0; r < 16; ++r) {
            int qr = (r & 3) + 8 * (r >> 2) + 4 * h;
            float iv = 1.f / lacc[r];
#pragma unroll
            for (int dt = 0; dt < 4; ++dt)
                XT[((size_t)b * N_ + q0 + qr) * C_ + g * D_ + dt * 32 + l31] =
                    (bf16)(oacc[dt][r] * iv);
        }
    }
}

// ---------- kernel 5: output projection, 128x64 tile; FUSE=1 merges the 2 KV-split
// partials during A-staging (reg-staged: load early, merge+ds_write after MFMAs) ----------
template<int FUSE>
__global__ __launch_bounds__(256) void oproj_kernel(const bf16* __restrict__ Ob,
                                                    const bf16* __restrict__ Op,
                                                    const float* __restrict__ ML,
                                                    const bf16* __restrict__ WB,
                                                    const float* __restrict__ bo,
                                                    const float* __restrict__ x,
                                                    float* __restrict__ out) {
    __shared__ char smem[24576];
    const int tid = threadIdx.x;
    const int w = tid >> 6, l = tid & 63;
    const int lr = l & 15, lg = l >> 4;
    const int wr = w >> 1, wc = w & 1;
    const bf16* W = WB + (size_t)3 * (C_ * C_);
    const int r0 = blockIdx.x * 128, o0 = blockIdx.y * 64;

    // A chunks: i=0 -> CL=tid, i=1 -> CL=tid+256; row=CL>>2, c=CL&3
    const char* srcA[2]; int dA[2], cpw[2]; size_t opRow[2];
    float w0f[2][4], w1f[2][4];
#pragma unroll
    for (int i = 0; i < 2; ++i) {
        int CL = tid + 256 * i, row = CL >> 2, c = CL & 3;
        cpw[i] = c ^ ((row >> 1) & 3);
        dA[i] = CL << 4;
        srcA[i] = (const char*)(Ob + (size_t)(r0 + row) * C_) + (cpw[i] << 4);
        if (FUSE) {
            int rg = r0 + row;
            int b = rg >> 12, n = rg & (N_ - 1);
            const float2* mlp = (const float2*)ML;
#pragma unroll
            for (int g = 0; g < 4; ++g) {
                int bg = b * 4 + g;
                float2 ml0 = mlp[(size_t)bg * N_ + n];
                float2 ml1 = mlp[(size_t)(8 + bg) * N_ + n];
                float mm = fmaxf(ml0.x, ml1.x);
                float a0 = __builtin_amdgcn_exp2f(ml0.x - mm);
                float a1 = __builtin_amdgcn_exp2f(ml1.x - mm);
                float inv = 1.f / (a0 * ml0.y + a1 * ml1.y);
                w0f[i][g] = a0 * inv;
                w1f[i][g] = a1 * inv;
            }
            opRow[i] = ((size_t)(b * 4) * N_ + n) * 256u;  // g=0 Op row base (bytes)
        }
    }
    const char* srcB; int dB;
    {
        int CL = tid, row = CL >> 2, c = CL & 3;
        srcB = (const char*)(W + (size_t)(o0 + row) * C_) + SWZ(row, c);
        dB = 8192 + (CL << 4);
    }

    f32x4 z = {0.f, 0.f, 0.f, 0.f};
    f32x4 acc[4][2];
#pragma unroll
    for (int m = 0; m < 4; ++m) { acc[m][0] = z; acc[m][1] = z; }

    uint4 a0r[2], a1r[2];
    auto LOAD_A = [&](int kt) {   // g = kt>>2 exactly (chunk never straddles heads)
        int g = kt >> 2;
#pragma unroll
        for (int i = 0; i < 2; ++i) {
            size_t off = opRow[i] + (size_t)g * ((size_t)N_ * 256u - 256u)
                       + (size_t)(kt * 64) + ((size_t)cpw[i] << 4);
            a0r[i] = *(const uint4*)((const char*)Op + off);
            a1r[i] = *(const uint4*)((const char*)Op + 8388608u + off);
        }
    };
    auto WRITE_A = [&](int buf, int kt) {
        int g = kt >> 2;
        char* base = smem + buf * 12288;
#pragma unroll
        for (int i = 0; i < 2; ++i) {
            union { uint4 u; bf16 h[8]; } u0, u1, uo;
            u0.u = a0r[i]; u1.u = a1r[i];
#pragma unroll
            for (int e = 0; e < 8; ++e)
                uo.h[e] = (bf16)(w0f[i][g] * (float)u0.h[e] + w1f[i][g] * (float)u1.h[e]);
            *(uint4*)(base + dA[i]) = uo.u;
        }
    };
    auto STAGE_A_PLAIN = [&](int buf, int kt) {
        char* base = smem + buf * 12288;
#pragma unroll
        for (int i = 0; i < 2; ++i) gload16(srcA[i] + kt * 64, base + dA[i]);
    };
    auto STAGE_B = [&](int buf, int kt) {
        gload16(srcB + kt * 64, smem + buf * 12288 + dB);
    };

    // prologue
    STAGE_B(0, 0);
    if (FUSE) { LOAD_A(0); WRITE_A(0, 0); }
    else       STAGE_A_PLAIN(0, 0);
    __syncthreads();

    for (int t = 0; t < 16; ++t) {
        int cur = t & 1;
        if (t < 15) {
            STAGE_B(cur ^ 1, t + 1);
            if (FUSE) LOAD_A(t + 1);           // issue early; merge+write after MFMAs
            else      STAGE_A_PLAIN(cur ^ 1, t + 1);
        }
        char* Ab = smem + cur * 12288;
        char* Bb = Ab + 8192;
        bf16x8 af[4], bg_[2];
#pragma unroll
        for (int m = 0; m < 4; ++m) {
            int row = wr * 64 + m * 16 + lr;
            af[m] = *(const bf16x8*)(Ab + row * 64 + SWZ(row, lg));
        }
#pragma unroll
        for (int n = 0; n < 2; ++n) {
            int row = wc * 32 + n * 16 + lr;
            bg_[n] = *(const bf16x8*)(Bb + row * 64 + SWZ(row, lg));
        }
#pragma unroll
        for (int m = 0; m < 4; ++m)
#pragma unroll
            for (int n = 0; n < 2; ++n)
                acc[m][n] = MFMA(af[m], bg_[n], acc[m][n], 0, 0, 0);
        if (FUSE && t < 15) WRITE_A(cur ^ 1, t + 1);   // buf[cur^1] readers done at t-1 sync
        __syncthreads();
    }

#pragma unroll
    for (int n = 0; n < 2; ++n) {
        int o = o0 + wc * 32 + n * 16 + lr;
        float bs = bo[o];
#pragma unroll
        for (int m = 0; m < 4; ++m) {
            int row = r0 + wr * 64 + m * 16 + lg * 4;
            int b = row >> 12, nn = row & (N_ - 1);
            size_t base = ((size_t)b * C_ + o) * N_ + nn;
            float4 xv = *(const float4*)(x + base);
            float4 ov;
            ov.x = acc[m][n][0] + bs + xv.x;
            ov.y = acc[m][n][1] + bs + xv.y;
            ov.z = acc[m][n][2] + bs + xv.z;
            ov.w = acc[m][n][3] + bs + xv.w;
            *(float4*)(out + base) = ov;
        }
    }
}

extern "C" void kernel_launch(void* const* d_in, const int* in_sizes, int n_in,
                              void* d_out, int out_size, void* d_ws, size_t ws_size,
                              hipStream_t stream) {
    const float* x  = (const float*)d_in[0];
    const float* Wq = (const float*)d_in[1];
    const float* bq = (const float*)d_in[2];
    const float* Wk = (const float*)d_in[3];
    const float* bk = (const float*)d_in[4];
    const float* Wv = (const float*)d_in[5];
    const float* bv = (const float*)d_in[6];
    const float* Wo = (const float*)d_in[7];
    const float* bo = (const float*)d_in[8];

    char* ws = (char*)d_ws;
    bf16* Q   = (bf16*)(ws + OFF_Q);
    bf16* K   = (bf16*)(ws + OFF_K);
    bf16* Vt  = (bf16*)(ws + OFF_VT);
    bf16* XT  = (bf16*)(ws + OFF_XT);
    bf16* WB  = (bf16*)(ws + OFF_WB);
    bf16* Op  = (bf16*)(ws + OFF_OP);
    float* ML = (float*)(ws + OFF_ML);
    float* out = (float*)d_out;

    hipLaunchKernelGGL(wcvt_kernel, dim3(256, 4), dim3(256), 0, stream, Wq, Wk, Wv, Wo, WB);
    hipLaunchKernelGGL(xt_kernel, dim3(64, 8, 2), dim3(256), 0, stream, x, XT);
    hipLaunchKernelGGL(qkv_kernel, dim3(64, 4, 3), dim3(256), 0, stream,
                       XT, WB, bq, bk, bv, Q, K, Vt);
    if (ws_size >= (size_t)WS_NEED_SPLIT) {
        hipLaunchKernelGGL(attn_kernel<2>, dim3(256), dim3(512), 0, stream,
                           Q, K, Vt, XT, Op, ML);
        hipLaunchKernelGGL(oproj_kernel<1>, dim3(64, 8), dim3(256), 0, stream,
                           XT, Op, ML, WB, bo, x, out);
    } else {
        hipLaunchKernelGGL(attn_kernel<1>, dim3(128), dim3(512), 0, stream,
                           Q, K, Vt, XT, Op, ML);
        hipLaunchKernelGGL(oproj_kernel<0>, dim3(64, 8), dim3(256), 0, stream,
                           XT, Op, ML, WB, bo, x, out);
    }
}

// Round 18
// 130.481 us; speedup vs baseline: 2.2274x; 1.0112x over previous
//
#include <hip/hip_runtime.h>
#include <hip/hip_bf16.h>
#include <stdint.h>

#define B_ 2
#define C_ 512
#define G_ 4
#define D_ 128
#define N_ 4096

typedef __bf16 bf16;
typedef __bf16 bf16x8 __attribute__((ext_vector_type(8)));
typedef float  f32x4  __attribute__((ext_vector_type(4)));
typedef float  f32x16 __attribute__((ext_vector_type(16)));

#define MFMA   __builtin_amdgcn_mfma_f32_16x16x32_bf16
#define MFMA32 __builtin_amdgcn_mfma_f32_32x32x16_bf16

// LDS chunk swizzle for GEMMs: physical chunk = logical chunk ^ ((row>>1)&3)
#define SWZ(row, c) ((((c) ^ (((row) >> 1) & 3)) << 4))

// ---- workspace layout (bytes) ----
#define OFF_Q   (0u)
#define OFF_K   (8388608u)
#define OFF_VT  (16777216u)
#define OFF_XT  (25165824u)
#define OFF_WB  (33554432u)
#define OFF_OP  (35651584u)
#define OFF_ML  (52428800u)
#define WS_NEED_SPLIT (52953088u)

__device__ inline unsigned pk2(float a, float b) {
    union { bf16 h[2]; unsigned u; } t;
    t.h[0] = (bf16)a; t.h[1] = (bf16)b;
    return t.u;
}
__device__ inline void pl32(unsigned &a, unsigned &b) {
    asm volatile("v_permlane32_swap_b32 %0, %1" : "+v"(a), "+v"(b));
}
__device__ inline void gload16(const char* src, char* lds) {
    __builtin_amdgcn_global_load_lds(
        (const __attribute__((address_space(1))) unsigned*)src,
        (__attribute__((address_space(3))) unsigned*)lds, 16, 0, 0);
}
__device__ inline float max3f(float a, float b, float c) {
    return fmaxf(fmaxf(a, b), c);
}

// ---------- kernel 1: weights fp32 -> bf16 ----------
__global__ __launch_bounds__(256) void wcvt_kernel(const float* __restrict__ Wq,
                                                   const float* __restrict__ Wk,
                                                   const float* __restrict__ Wv,
                                                   const float* __restrict__ Wo,
                                                   bf16* __restrict__ out) {
    int m = blockIdx.y;
    const float* W = (m == 0) ? Wq : (m == 1) ? Wk : (m == 2) ? Wv : Wo;
    int i = (blockIdx.x * 256 + threadIdx.x) * 4;
    float4 v = *(const float4*)(W + i);
    union { bf16 h[4]; uint2 u; } pk;
    pk.h[0] = (bf16)v.x; pk.h[1] = (bf16)v.y; pk.h[2] = (bf16)v.z; pk.h[3] = (bf16)v.w;
    *(uint2*)(out + (size_t)m * (C_ * C_) + i) = pk.u;
}

// ---------- kernel 2: x [b][c][n] f32 -> xT [b*n][c] bf16 ----------
__global__ __launch_bounds__(256) void xt_kernel(const float* __restrict__ x,
                                                 bf16* __restrict__ xT) {
    __shared__ bf16 t[64 * 80];
    int n0 = blockIdx.x * 64, c0 = blockIdx.y * 64, b = blockIdx.z;
    const float* xp = x + (size_t)b * C_ * N_;
#pragma unroll
    for (int i = 0; i < 16; ++i) {
        int idx = threadIdx.x + 256 * i;
        int cl = idx >> 6, nl = idx & 63;
        float v = xp[(size_t)(c0 + cl) * N_ + n0 + nl];
        t[nl * 80 + cl] = (bf16)v;
    }
    __syncthreads();
    bf16* xt = xT + ((size_t)b * N_ + n0) * C_ + c0;
#pragma unroll
    for (int i = 0; i < 2; ++i) {
        int id = threadIdx.x + 256 * i;
        int nl = id >> 3, c8 = (id & 7) * 8;
        *(uint4*)(xt + (size_t)nl * C_ + c8) = *(const uint4*)(t + nl * 80 + c8);
    }
}

// ---------- kernel 3: fused QKV projection, 128x128 tile ----------
__global__ __launch_bounds__(256) void qkv_kernel(const bf16* __restrict__ xT,
                                                  const bf16* __restrict__ WB,
                                                  const float* __restrict__ bq,
                                                  const float* __restrict__ bk,
                                                  const float* __restrict__ bv,
                                                  bf16* __restrict__ Q,
                                                  bf16* __restrict__ K,
                                                  bf16* __restrict__ Vt) {
    __shared__ char smem[32768];
    const int tid = threadIdx.x;
    const int w = tid >> 6, l = tid & 63;
    const int lr = l & 15, lg = l >> 4;
    const int wr = w >> 1, wc = w & 1;
    const int mat = blockIdx.z;
    const bf16* A = xT;
    const bf16* W = WB + (size_t)mat * (C_ * C_);
    const float* bias = (mat == 0) ? bq : (mat == 1) ? bk : bv;
    const int r0 = blockIdx.x * 128, o0 = blockIdx.y * 128;
    const float QSCALE = 0.08838834764831845f * 1.4426950408889634f;

    const char* srcA[2]; const char* srcB[2]; int dA[2], dB[2];
#pragma unroll
    for (int i = 0; i < 2; ++i) {
        int CL = tid + 256 * i, row = CL >> 2, c = CL & 3;
        srcA[i] = (const char*)(A + (size_t)(r0 + row) * C_) + SWZ(row, c);
        srcB[i] = (const char*)(W + (size_t)(o0 + row) * C_) + SWZ(row, c);
        dA[i] = CL << 4;
        dB[i] = 8192 + (CL << 4);
    }

    f32x4 z = {0.f, 0.f, 0.f, 0.f};
    f32x4 acc[4][4];
#pragma unroll
    for (int m = 0; m < 4; ++m)
#pragma unroll
        for (int n = 0; n < 4; ++n) acc[m][n] = z;

    auto STAGE = [&](int buf, int kt) {
        char* base = smem + buf * 16384;
        int kb = kt * 64;
#pragma unroll
        for (int i = 0; i < 2; ++i) {
            gload16(srcA[i] + kb, base + dA[i]);
            gload16(srcB[i] + kb, base + dB[i]);
        }
    };

    STAGE(0, 0);
    __syncthreads();
#pragma unroll 4
    for (int t = 0; t < 16; ++t) {
        int cur = t & 1;
        if (t < 15) STAGE(cur ^ 1, t + 1);
        char* Ab = smem + cur * 16384;
        char* Bb = Ab + 8192;
        bf16x8 af[4], bg_[4];
#pragma unroll
        for (int m = 0; m < 4; ++m) {
            int row = wr * 64 + m * 16 + lr;
            af[m] = *(const bf16x8*)(Ab + row * 64 + SWZ(row, lg));
        }
#pragma unroll
        for (int n = 0; n < 4; ++n) {
            int row = wc * 64 + n * 16 + lr;
            bg_[n] = *(const bf16x8*)(Bb + row * 64 + SWZ(row, lg));
        }
#pragma unroll
        for (int m = 0; m < 4; ++m)
#pragma unroll
            for (int n = 0; n < 4; ++n)
                acc[m][n] = MFMA(af[m], bg_[n], acc[m][n], 0, 0, 0);
        __syncthreads();
    }

#pragma unroll
    for (int n = 0; n < 4; ++n) {
        int o = o0 + wc * 64 + n * 16 + lr;
        float bs = bias[o];
        int g = o >> 7, d = o & 127;
#pragma unroll
        for (int m = 0; m < 4; ++m) {
            int row = r0 + wr * 64 + m * 16 + lg * 4;
            int b = row >> 12, nn = row & (N_ - 1);
            if (mat == 0) {
#pragma unroll
                for (int j = 0; j < 4; ++j)
                    Q[((size_t)(b * G_ + g) * N_ + nn + j) * D_ + d] =
                        (bf16)((acc[m][n][j] + bs) * QSCALE);
            } else if (mat == 1) {
#pragma unroll
                for (int j = 0; j < 4; ++j)
                    K[((size_t)(b * G_ + g) * N_ + nn + j) * D_ + d] =
                        (bf16)(acc[m][n][j] + bs);
            } else {
                union { bf16 h[4]; uint2 u; } pk;
#pragma unroll
                for (int j = 0; j < 4; ++j) pk.h[j] = (bf16)(acc[m][n][j] + bs);
                *(uint2*)(Vt + ((size_t)(b * G_ + g) * D_ + d) * N_ + nn) = pk.u;
            }
        }
    }
}

// ================= shared attention tile body =================
struct AttnState {
    f32x16 oacc[4], lacc;
    float mrun;
};

template<typename T>
__device__ inline void attn_tile_body(AttnState& st, const bf16x8* aq,
                                      const bf16x8& ones, char* Kb, char* Vb,
                                      int l31, int h, T) {
    const float THR = 5.0f;
    f32x16 s0, s1;
#pragma unroll
    for (int r = 0; r < 16; ++r) { s0[r] = 0.f; s1[r] = 0.f; }
    __builtin_amdgcn_s_setprio(1);
#pragma unroll
    for (int kb = 0; kb < 8; ++kb) {
        int ch = (((kb << 1) | h) ^ (l31 & 15)) << 4;
        bf16x8 kf0 = *(const bf16x8*)(Kb + (size_t)l31 * 256 + ch);
        s0 = MFMA32(kf0, aq[kb], s0, 0, 0, 0);
        bf16x8 kf1 = *(const bf16x8*)(Kb + (size_t)(32 + l31) * 256 + ch);
        s1 = MFMA32(kf1, aq[kb], s1, 0, 0, 0);
    }
    __builtin_amdgcn_s_setprio(0);

    float x0 = max3f(s0[0],  s0[1],  s0[2]);
    float x1 = max3f(s0[3],  s0[4],  s0[5]);
    float x2 = max3f(s0[6],  s0[7],  s0[8]);
    float x3 = max3f(s0[9],  s0[10], s0[11]);
    float x4 = max3f(s0[12], s0[13], s0[14]);
    float x5 = max3f(s0[15], s1[0],  s1[1]);
    float x6 = max3f(s1[2],  s1[3],  s1[4]);
    float x7 = max3f(s1[5],  s1[6],  s1[7]);
    float x8 = max3f(s1[8],  s1[9],  s1[10]);
    float x9 = max3f(s1[11], s1[12], s1[13]);
    float xa = fmaxf(s1[14], s1[15]);
    float y0 = max3f(x0, x1, x2);
    float y1 = max3f(x3, x4, x5);
    float y2 = max3f(x6, x7, x8);
    float y3 = fmaxf(x9, xa);
    float mt = fmaxf(max3f(y0, y1, y2), y3);
    mt = fmaxf(mt, __shfl_xor(mt, 32));

    if (__any(mt > st.mrun + THR)) {
        float mn = fmaxf(st.mrun, mt);
        float corr = __builtin_amdgcn_exp2f(st.mrun - mn);
        st.mrun = mn;
#pragma unroll
        for (int r = 0; r < 16; ++r) {
            int qr = (r & 3) + 8 * (r >> 2) + 4 * h;
            float cr = __shfl(corr, qr);
            st.lacc[r] *= cr;
#pragma unroll
            for (int dt = 0; dt < 4; ++dt) st.oacc[dt][r] *= cr;
        }
    }

#pragma unroll
    for (int r = 0; r < 16; ++r) {
        s0[r] = __builtin_amdgcn_exp2f(s0[r] - st.mrun);
        s1[r] = __builtin_amdgcn_exp2f(s1[r] - st.mrun);
    }

    bf16x8 pa0, pa1, pa2, pa3;
    {
        unsigned u0 = pk2(s0[0], s0[1]),  v0 = pk2(s0[4], s0[5]);  pl32(u0, v0);
        unsigned u1 = pk2(s0[2], s0[3]),  v1 = pk2(s0[6], s0[7]);  pl32(u1, v1);
        pa0 = __builtin_bit_cast(bf16x8, (uint4){u0, u1, v0, v1});
        unsigned u2 = pk2(s0[8], s0[9]),  v2 = pk2(s0[12], s0[13]); pl32(u2, v2);
        unsigned u3 = pk2(s0[10], s0[11]), v3 = pk2(s0[14], s0[15]); pl32(u3, v3);
        pa1 = __builtin_bit_cast(bf16x8, (uint4){u2, u3, v2, v3});
        unsigned u4 = pk2(s1[0], s1[1]),  v4 = pk2(s1[4], s1[5]);  pl32(u4, v4);
        unsigned u5 = pk2(s1[2], s1[3]),  v5 = pk2(s1[6], s1[7]);  pl32(u5, v5);
        pa2 = __builtin_bit_cast(bf16x8, (uint4){u4, u5, v4, v5});
        unsigned u6 = pk2(s1[8], s1[9]),  v6 = pk2(s1[12], s1[13]); pl32(u6, v6);
        unsigned u7 = pk2(s1[10], s1[11]), v7 = pk2(s1[14], s1[15]); pl32(u7, v7);
        pa3 = __builtin_bit_cast(bf16x8, (uint4){u6, u7, v6, v7});
    }

    __builtin_amdgcn_s_setprio(1);
#pragma unroll
    for (int sl = 0; sl < 4; ++sl) {
        bf16x8 pa = (sl == 0) ? pa0 : (sl == 1) ? pa1 : (sl == 2) ? pa2 : pa3;
#pragma unroll
        for (int dt = 0; dt < 4; ++dt) {
            int row = dt * 16 + (l31 >> 1);
            int ch = ((((l31 & 1) << 3) + (sl << 1) + h) ^ (l31 >> 1)) << 4;
            bf16x8 vf = *(const bf16x8*)(Vb + (size_t)row * 256 + ch);
            st.oacc[dt] = MFMA32(pa, vf, st.oacc[dt], 0, 0, 0);
        }
        st.lacc = MFMA32(pa, ones, st.lacc, 0, 0, 0);
    }
    __builtin_amdgcn_s_setprio(0);
}

__device__ inline void attn_epilogue(AttnState& st, int sp, int bg, int q0,
                                     int l, int l31, int h,
                                     bf16* Op, float* ML) {
    float2* mlp = (float2*)ML + ((size_t)sp * 8 + bg) * N_ + q0;
#pragma unroll
    for (int r = 0; r < 16; ++r) {
        int qr = (r & 3) + 8 * (r >> 2) + 4 * h;
        float mv = __shfl(st.mrun, qr);
        if (l31 == 0) {
            float2 v; v.x = mv; v.y = st.lacc[r];
            mlp[qr] = v;
        }
    }
    bf16* op = Op + (((size_t)sp * 8 + bg) * N_ + q0) * D_;
#pragma unroll
    for (int dt = 0; dt < 4; ++dt)
#pragma unroll
        for (int r = 0; r < 16; ++r) {
            int qr = (r & 3) + 8 * (r >> 2) + 4 * h;
            op[(size_t)qr * D_ + dt * 32 + l31] = (bf16)st.oacc[dt][r];
        }
}

// ---------- kernel 4a: r13/r16 attention (64-kv tiles, static 64KB LDS) ----------
template<int SPLITS>
__global__ __launch_bounds__(512, 2) void attn_kernel(const bf16* __restrict__ Q,
                                                      const bf16* __restrict__ K,
                                                      const bf16* __restrict__ Vt,
                                                      bf16* __restrict__ XT,
                                                      bf16* __restrict__ Op,
                                                      float* __restrict__ ML) {
    __shared__ char smem[65536];
    const int tid = threadIdx.x;
    const int w = tid >> 6, l = tid & 63;
    const int l31 = l & 31, h = l >> 5;

    const int L = blockIdx.x;
    const int bg = L & 7;
    const int ix = L >> 3;
    const int sp = (SPLITS > 1) ? (ix >> 4) : 0;
    const int qb = (SPLITS > 1) ? (ix & 15) : ix;

    const bf16* Qh = Q + (size_t)bg * N_ * D_;
    const char* Kh = (const char*)(K + (size_t)bg * N_ * D_);
    const char* Vh = (const char*)(Vt + (size_t)bg * D_ * N_);
    const int q0 = qb * 256 + w * 32;
    const int kv0 = sp * (N_ / SPLITS);
    const int NT = N_ / SPLITS / 64;

    int offK[2], offV[2];
#pragma unroll
    for (int j = 0; j < 2; ++j) {
        int CL = (w * 2 + j) * 64 + l;
        int row = CL >> 4;
        int cp = (CL & 15) ^ (row & 15);
        offK[j] = row * 256 + cp * 16;
        int dv = 2 * row + (cp >> 3), k8 = cp & 7;
        offV[j] = dv * (N_ * 2) + k8 * 16;
    }

    bf16x8 aq[8];
#pragma unroll
    for (int kb = 0; kb < 8; ++kb)
        aq[kb] = *(const bf16x8*)(Qh + (size_t)(q0 + l31) * D_ + kb * 16 + h * 8);

    bf16 one_ = (bf16)1.0f;
    bf16x8 ones = {one_, one_, one_, one_, one_, one_, one_, one_};

    AttnState st;
#pragma unroll
    for (int dt = 0; dt < 4; ++dt)
#pragma unroll
        for (int r = 0; r < 16; ++r) st.oacc[dt][r] = 0.f;
#pragma unroll
    for (int r = 0; r < 16; ++r) st.lacc[r] = 0.f;
    st.mrun = -1e30f;

    auto STAGE = [&](int buf, int kv) {
        const char* pk = Kh + (size_t)kv * 256;
        const char* pv = Vh + (size_t)kv * 2;
        char* kb = smem + buf * 32768 + w * 2048;
        char* vb = smem + buf * 32768 + 16384 + w * 2048;
#pragma unroll
        for (int j = 0; j < 2; ++j) gload16(pk + offK[j], kb + j * 1024);
#pragma unroll
        for (int j = 0; j < 2; ++j) gload16(pv + offV[j], vb + j * 1024);
    };

    STAGE(0, kv0);

    for (int t = 0; t < NT; ++t) {
        int cur = t & 1;
        __builtin_amdgcn_s_barrier();
        if (t + 1 < NT) {
            STAGE(cur ^ 1, kv0 + (t + 1) * 64);
            asm volatile("s_waitcnt vmcnt(4)" ::: "memory");
        } else {
            asm volatile("s_waitcnt vmcnt(0)" ::: "memory");
        }
        __builtin_amdgcn_sched_barrier(0);
        __builtin_amdgcn_s_barrier();
        attn_tile_body(st, aq, ones, smem + cur * 32768,
                       smem + cur * 32768 + 16384, l31, h, 0);
    }

    if (SPLITS > 1) {
        attn_epilogue(st, sp, bg, q0, l, l31, h, Op, ML);
    } else {
        int b = bg >> 2, g = bg & 3;
#pragma unroll
        for (int r = 0; r < 16; ++r) {
            int qr = (r & 3) + 8 * (r >> 2) + 4 * h;
            float iv = 1.f / st.lacc[r];
#pragma unroll
            for (int dt = 0; dt < 4; ++dt)
                XT[((size_t)b * N_ + q0 + qr) * C_ + g * D_ + dt * 32 + l31] =
                    (bf16)(st.oacc[dt][r] * iv);
        }
    }
}

// ---------- kernel 4b: 128-kv staged tiles, dynamic 128KB LDS (half the barriers) ----------
__global__ __launch_bounds__(512, 1) void attn_big_kernel(const bf16* __restrict__ Q,
                                                          const bf16* __restrict__ K,
                                                          const bf16* __restrict__ Vt,
                                                          bf16* __restrict__ Op,
                                                          float* __restrict__ ML) {
    extern __shared__ char smem[];   // 2 bufs x (K 32KB + V 32KB) = 128KB
    const int tid = threadIdx.x;
    const int w = tid >> 6, l = tid & 63;
    const int l31 = l & 31, h = l >> 5;

    const int L = blockIdx.x;        // 256 blocks (SPLITS=2 layout)
    const int bg = L & 7;
    const int ix = L >> 3;
    const int sp = ix >> 4;
    const int qb = ix & 15;

    const bf16* Qh = Q + (size_t)bg * N_ * D_;
    const char* Kh = (const char*)(K + (size_t)bg * N_ * D_);
    const char* Vh = (const char*)(Vt + (size_t)bg * D_ * N_);
    const int q0 = qb * 256 + w * 32;
    const int kv0 = sp * (N_ / 2);
    const int NT = (N_ / 2) / 128;   // 16 staged tiles of 128 kv

    int offK[2], offV[2];
#pragma unroll
    for (int j = 0; j < 2; ++j) {
        int CL = (w * 2 + j) * 64 + l;
        int row = CL >> 4;
        int cp = (CL & 15) ^ (row & 15);
        offK[j] = row * 256 + cp * 16;
        int dv = 2 * row + (cp >> 3), k8 = cp & 7;
        offV[j] = dv * (N_ * 2) + k8 * 16;
    }

    bf16x8 aq[8];
#pragma unroll
    for (int kb = 0; kb < 8; ++kb)
        aq[kb] = *(const bf16x8*)(Qh + (size_t)(q0 + l31) * D_ + kb * 16 + h * 8);

    bf16 one_ = (bf16)1.0f;
    bf16x8 ones = {one_, one_, one_, one_, one_, one_, one_, one_};

    AttnState st;
#pragma unroll
    for (int dt = 0; dt < 4; ++dt)
#pragma unroll
        for (int r = 0; r < 16; ++r) st.oacc[dt][r] = 0.f;
#pragma unroll
    for (int r = 0; r < 16; ++r) st.lacc[r] = 0.f;
    st.mrun = -1e30f;

    // stage 128 kv = two 64-kv sub-tiles; 8 gloads/wave per staged tile
    auto STAGE = [&](int buf, int kv) {
#pragma unroll
        for (int s2 = 0; s2 < 2; ++s2) {
            const char* pk = Kh + (size_t)(kv + 64 * s2) * 256;
            const char* pv = Vh + (size_t)(kv + 64 * s2) * 2;
            char* kb = smem + buf * 65536 + s2 * 16384 + w * 2048;
            char* vb = smem + buf * 65536 + 32768 + s2 * 16384 + w * 2048;
#pragma unroll
            for (int j = 0; j < 2; ++j) gload16(pk + offK[j], kb + j * 1024);
#pragma unroll
            for (int j = 0; j < 2; ++j) gload16(pv + offV[j], vb + j * 1024);
        }
    };

    STAGE(0, kv0);

    for (int t = 0; t < NT; ++t) {
        int cur = t & 1;
        __builtin_amdgcn_s_barrier();
        if (t + 1 < NT) {
            STAGE(cur ^ 1, kv0 + (t + 1) * 128);
            asm volatile("s_waitcnt vmcnt(8)" ::: "memory");  // drain tile t's 8
        } else {
            asm volatile("s_waitcnt vmcnt(0)" ::: "memory");
        }
        __builtin_amdgcn_sched_barrier(0);
        __builtin_amdgcn_s_barrier();
#pragma unroll
        for (int s2 = 0; s2 < 2; ++s2)
            attn_tile_body(st, aq, ones,
                           smem + cur * 65536 + s2 * 16384,
                           smem + cur * 65536 + 32768 + s2 * 16384, l31, h, 0);
    }

    attn_epilogue(st, sp, bg, q0, l, l31, h, Op, ML);
}

// ---------- kernel 5: output projection + fused KV-split merge ----------
template<int FUSE>
__global__ __launch_bounds__(256) void oproj_kernel(const bf16* __restrict__ Ob,
                                                    const bf16* __restrict__ Op,
                                                    const float* __restrict__ ML,
                                                    const bf16* __restrict__ WB,
                                                    const float* __restrict__ bo,
                                                    const float* __restrict__ x,
                                                    float* __restrict__ out) {
    __shared__ char smem[24576];
    const int tid = threadIdx.x;
    const int w = tid >> 6, l = tid & 63;
    const int lr = l & 15, lg = l >> 4;
    const int wr = w >> 1, wc = w & 1;
    const bf16* W = WB + (size_t)3 * (C_ * C_);
    const int r0 = blockIdx.x * 128, o0 = blockIdx.y * 64;

    const char* srcA[2]; int dA[2], cpw[2]; size_t opRow[2];
    float w0f[2][4], w1f[2][4];
#pragma unroll
    for (int i = 0; i < 2; ++i) {
        int CL = tid + 256 * i, row = CL >> 2, c = CL & 3;
        cpw[i] = c ^ ((row >> 1) & 3);
        dA[i] = CL << 4;
        srcA[i] = (const char*)(Ob + (size_t)(r0 + row) * C_) + (cpw[i] << 4);
        if (FUSE) {
            int rg = r0 + row;
            int b = rg >> 12, n = rg & (N_ - 1);
            const float2* mlp = (const float2*)ML;
#pragma unroll
            for (int g = 0; g < 4; ++g) {
                int bg = b * 4 + g;
                float2 ml0 = mlp[(size_t)bg * N_ + n];
                float2 ml1 = mlp[(size_t)(8 + bg) * N_ + n];
                float mm = fmaxf(ml0.x, ml1.x);
                float a0 = __builtin_amdgcn_exp2f(ml0.x - mm);
                float a1 = __builtin_amdgcn_exp2f(ml1.x - mm);
                float inv = 1.f / (a0 * ml0.y + a1 * ml1.y);
                w0f[i][g] = a0 * inv;
                w1f[i][g] = a1 * inv;
            }
            opRow[i] = ((size_t)(b * 4) * N_ + n) * 256u;
        }
    }
    const char* srcB; int dB;
    {
        int CL = tid, row = CL >> 2, c = CL & 3;
        srcB = (const char*)(W + (size_t)(o0 + row) * C_) + SWZ(row, c);
        dB = 8192 + (CL << 4);
    }

    f32x4 z = {0.f, 0.f, 0.f, 0.f};
    f32x4 acc[4][2];
#pragma unroll
    for (int m = 0; m < 4; ++m) { acc[m][0] = z; acc[m][1] = z; }

    uint4 a0r[2], a1r[2];
    auto LOAD_A = [&](int kt) {
        int g = kt >> 2;
#pragma unroll
        for (int i = 0; i < 2; ++i) {
            size_t off = opRow[i] + (size_t)g * ((size_t)N_ * 256u - 256u)
                       + (size_t)(kt * 64) + ((size_t)cpw[i] << 4);
            a0r[i] = *(const uint4*)((const char*)Op + off);
            a1r[i] = *(const uint4*)((const char*)Op + 8388608u + off);
        }
    };
    auto WRITE_A = [&](int buf, int kt) {
        int g = kt >> 2;
        char* base = smem + buf * 12288;
#pragma unroll
        for (int i = 0; i < 2; ++i) {
            union { uint4 u; bf16 h[8]; } u0, u1, uo;
            u0.u = a0r[i]; u1.u = a1r[i];
#pragma unroll
            for (int e = 0; e < 8; ++e)
                uo.h[e] = (bf16)(w0f[i][g] * (float)u0.h[e] + w1f[i][g] * (float)u1.h[e]);
            *(uint4*)(base + dA[i]) = uo.u;
        }
    };
    auto STAGE_A_PLAIN = [&](int buf, int kt) {
        char* base = smem + buf * 12288;
#pragma unroll
        for (int i = 0; i < 2; ++i) gload16(srcA[i] + kt * 64, base + dA[i]);
    };
    auto STAGE_B = [&](int buf, int kt) {
        gload16(srcB + kt * 64, smem + buf * 12288 + dB);
    };

    STAGE_B(0, 0);
    if (FUSE) { LOAD_A(0); WRITE_A(0, 0); }
    else       STAGE_A_PLAIN(0, 0);
    __syncthreads();

    for (int t = 0; t < 16; ++t) {
        int cur = t & 1;
        if (t < 15) {
            STAGE_B(cur ^ 1, t + 1);
            if (FUSE) LOAD_A(t + 1);
            else      STAGE_A_PLAIN(cur ^ 1, t + 1);
        }
        char* Ab = smem + cur * 12288;
        char* Bb = Ab + 8192;
        bf16x8 af[4], bg_[2];
#pragma unroll
        for (int m = 0; m < 4; ++m) {
            int row = wr * 64 + m * 16 + lr;
            af[m] = *(const bf16x8*)(Ab + row * 64 + SWZ(row, lg));
        }
#pragma unroll
        for (int n = 0; n < 2; ++n) {
            int row = wc * 32 + n * 16 + lr;
            bg_[n] = *(const bf16x8*)(Bb + row * 64 + SWZ(row, lg));
        }
#pragma unroll
        for (int m = 0; m < 4; ++m)
#pragma unroll
            for (int n = 0; n < 2; ++n)
                acc[m][n] = MFMA(af[m], bg_[n], acc[m][n], 0, 0, 0);
        if (FUSE && t < 15) WRITE_A(cur ^ 1, t + 1);
        __syncthreads();
    }

#pragma unroll
    for (int n = 0; n < 2; ++n) {
        int o = o0 + wc * 32 + n * 16 + lr;
        float bs = bo[o];
#pragma unroll
        for (int m = 0; m < 4; ++m) {
            int row = r0 + wr * 64 + m * 16 + lg * 4;
            int b = row >> 12, nn = row & (N_ - 1);
            size_t base = ((size_t)b * C_ + o) * N_ + nn;
            float4 xv = *(const float4*)(x + base);
            float4 ov;
            ov.x = acc[m][n][0] + bs + xv.x;
            ov.y = acc[m][n][1] + bs + xv.y;
            ov.z = acc[m][n][2] + bs + xv.z;
            ov.w = acc[m][n][3] + bs + xv.w;
            *(float4*)(out + base) = ov;
        }
    }
}

extern "C" void kernel_launch(void* const* d_in, const int* in_sizes, int n_in,
                              void* d_out, int out_size, void* d_ws, size_t ws_size,
                              hipStream_t stream) {
    const float* x  = (const float*)d_in[0];
    const float* Wq = (const float*)d_in[1];
    const float* bq = (const float*)d_in[2];
    const float* Wk = (const float*)d_in[3];
    const float* bk = (const float*)d_in[4];
    const float* Wv = (const float*)d_in[5];
    const float* bv = (const float*)d_in[6];
    const float* Wo = (const float*)d_in[7];
    const float* bo = (const float*)d_in[8];

    char* ws = (char*)d_ws;
    bf16* Q   = (bf16*)(ws + OFF_Q);
    bf16* K   = (bf16*)(ws + OFF_K);
    bf16* Vt  = (bf16*)(ws + OFF_VT);
    bf16* XT  = (bf16*)(ws + OFF_XT);
    bf16* WB  = (bf16*)(ws + OFF_WB);
    bf16* Op  = (bf16*)(ws + OFF_OP);
    float* ML = (float*)(ws + OFF_ML);
    float* out = (float*)d_out;

    hipLaunchKernelGGL(wcvt_kernel, dim3(256, 4), dim3(256), 0, stream, Wq, Wk, Wv, Wo, WB);
    hipLaunchKernelGGL(xt_kernel, dim3(64, 8, 2), dim3(256), 0, stream, x, XT);
    hipLaunchKernelGGL(qkv_kernel, dim3(64, 4, 3), dim3(256), 0, stream,
                       XT, WB, bq, bk, bv, Q, K, Vt);
    if (ws_size >= (size_t)WS_NEED_SPLIT) {
        // try the 128KB-LDS big-tile kernel; fall back to the proven r13 kernel
        hipError_t e = hipFuncSetAttribute(
            reinterpret_cast<const void*>(&attn_big_kernel),
            hipFuncAttributeMaxDynamicSharedMemorySize, 131072);
        if (e == hipSuccess) {
            hipLaunchKernelGGL(attn_big_kernel, dim3(256), dim3(512), 131072, stream,
                               Q, K, Vt, Op, ML);
        } else {
            hipLaunchKernelGGL(attn_kernel<2>, dim3(256), dim3(512), 0, stream,
                               Q, K, Vt, XT, Op, ML);
        }
        hipLaunchKernelGGL(oproj_kernel<1>, dim3(64, 8), dim3(256), 0, stream,
                           XT, Op, ML, WB, bo, x, out);
    } else {
        hipLaunchKernelGGL(attn_kernel<1>, dim3(128), dim3(512), 0, stream,
                           Q, K, Vt, XT, Op, ML);
        hipLaunchKernelGGL(oproj_kernel<0>, dim3(64, 8), dim3(256), 0, stream,
                           XT, Op, ML, WB, bo, x, out);
    }
}

// Round 19
// 126.778 us; speedup vs baseline: 2.2924x; 1.0292x over previous
//
#include <hip/hip_runtime.h>
#include <hip/hip_bf16.h>
#include <stdint.h>

#define B_ 2
#define C_ 512
#define G_ 4
#define D_ 128
#define N_ 4096

typedef __bf16 bf16;
typedef __bf16 bf16x8 __attribute__((ext_vector_type(8)));
typedef float  f32x4  __attribute__((ext_vector_type(4)));
typedef float  f32x16 __attribute__((ext_vector_type(16)));

#define MFMA   __builtin_amdgcn_mfma_f32_16x16x32_bf16
#define MFMA32 __builtin_amdgcn_mfma_f32_32x32x16_bf16

// LDS chunk swizzle for GEMMs: physical chunk = logical chunk ^ ((row>>1)&3)
#define SWZ(row, c) ((((c) ^ (((row) >> 1) & 3)) << 4))

// ---- workspace layout (bytes) ----
#define OFF_Q   (0u)
#define OFF_K   (8388608u)
#define OFF_VT  (16777216u)
#define OFF_XT  (25165824u)
#define OFF_WB  (33554432u)
#define OFF_OP  (35651584u)
#define OFF_ML  (52428800u)
#define WS_NEED_SPLIT (52953088u)

__device__ inline unsigned pk2(float a, float b) {
    union { bf16 h[2]; unsigned u; } t;
    t.h[0] = (bf16)a; t.h[1] = (bf16)b;
    return t.u;
}
__device__ inline void pl32(unsigned &a, unsigned &b) {
    asm volatile("v_permlane32_swap_b32 %0, %1" : "+v"(a), "+v"(b));
}
__device__ inline void gload16(const char* src, char* lds) {
    __builtin_amdgcn_global_load_lds(
        (const __attribute__((address_space(1))) unsigned*)src,
        (__attribute__((address_space(3))) unsigned*)lds, 16, 0, 0);
}
__device__ inline float max3f(float a, float b, float c) {
    return fmaxf(fmaxf(a, b), c);
}

// ---------- kernel 1: fused prep (weights fp32->bf16  |  x -> xT bf16) ----------
// blocks [0,1024): wcvt; blocks [1024,2048): xt. Independent outputs (WB vs XT).
__global__ __launch_bounds__(256) void prep_kernel(const float* __restrict__ Wq,
                                                   const float* __restrict__ Wk,
                                                   const float* __restrict__ Wv,
                                                   const float* __restrict__ Wo,
                                                   bf16* __restrict__ WBo,
                                                   const float* __restrict__ x,
                                                   bf16* __restrict__ xT) {
    __shared__ bf16 t[64 * 80];
    const int gid = blockIdx.x;
    if (gid < 1024) {
        int m = gid >> 8, xb = gid & 255;
        const float* W = (m == 0) ? Wq : (m == 1) ? Wk : (m == 2) ? Wv : Wo;
        int i = (xb * 256 + threadIdx.x) * 4;
        float4 v = *(const float4*)(W + i);
        union { bf16 h[4]; uint2 u; } pk;
        pk.h[0] = (bf16)v.x; pk.h[1] = (bf16)v.y; pk.h[2] = (bf16)v.z; pk.h[3] = (bf16)v.w;
        *(uint2*)(WBo + (size_t)m * (C_ * C_) + i) = pk.u;
        return;
    }
    int id = gid - 1024;
    int b = id >> 9, c0 = ((id >> 6) & 7) * 64, n0 = (id & 63) * 64;
    const float* xp = x + (size_t)b * C_ * N_;
#pragma unroll
    for (int i = 0; i < 16; ++i) {
        int idx = threadIdx.x + 256 * i;
        int cl = idx >> 6, nl = idx & 63;
        float v = xp[(size_t)(c0 + cl) * N_ + n0 + nl];
        t[nl * 80 + cl] = (bf16)v;
    }
    __syncthreads();
    bf16* xt = xT + ((size_t)b * N_ + n0) * C_ + c0;
#pragma unroll
    for (int i = 0; i < 2; ++i) {
        int iid = threadIdx.x + 256 * i;
        int nl = iid >> 3, c8 = (iid & 7) * 8;
        *(uint4*)(xt + (size_t)nl * C_ + c8) = *(const uint4*)(t + nl * 80 + c8);
    }
}

// ---------- kernel 3: fused QKV projection, 128x128 tile ----------
__global__ __launch_bounds__(256) void qkv_kernel(const bf16* __restrict__ xT,
                                                  const bf16* __restrict__ WB,
                                                  const float* __restrict__ bq,
                                                  const float* __restrict__ bk,
                                                  const float* __restrict__ bv,
                                                  bf16* __restrict__ Q,
                                                  bf16* __restrict__ K,
                                                  bf16* __restrict__ Vt) {
    __shared__ char smem[32768];
    const int tid = threadIdx.x;
    const int w = tid >> 6, l = tid & 63;
    const int lr = l & 15, lg = l >> 4;
    const int wr = w >> 1, wc = w & 1;
    const int mat = blockIdx.z;
    const bf16* A = xT;
    const bf16* W = WB + (size_t)mat * (C_ * C_);
    const float* bias = (mat == 0) ? bq : (mat == 1) ? bk : bv;
    const int r0 = blockIdx.x * 128, o0 = blockIdx.y * 128;
    const float QSCALE = 0.08838834764831845f * 1.4426950408889634f;

    const char* srcA[2]; const char* srcB[2]; int dA[2], dB[2];
#pragma unroll
    for (int i = 0; i < 2; ++i) {
        int CL = tid + 256 * i, row = CL >> 2, c = CL & 3;
        srcA[i] = (const char*)(A + (size_t)(r0 + row) * C_) + SWZ(row, c);
        srcB[i] = (const char*)(W + (size_t)(o0 + row) * C_) + SWZ(row, c);
        dA[i] = CL << 4;
        dB[i] = 8192 + (CL << 4);
    }

    f32x4 z = {0.f, 0.f, 0.f, 0.f};
    f32x4 acc[4][4];
#pragma unroll
    for (int m = 0; m < 4; ++m)
#pragma unroll
        for (int n = 0; n < 4; ++n) acc[m][n] = z;

    auto STAGE = [&](int buf, int kt) {
        char* base = smem + buf * 16384;
        int kb = kt * 64;
#pragma unroll
        for (int i = 0; i < 2; ++i) {
            gload16(srcA[i] + kb, base + dA[i]);
            gload16(srcB[i] + kb, base + dB[i]);
        }
    };

    STAGE(0, 0);
    __syncthreads();
#pragma unroll 4
    for (int t = 0; t < 16; ++t) {
        int cur = t & 1;
        if (t < 15) STAGE(cur ^ 1, t + 1);
        char* Ab = smem + cur * 16384;
        char* Bb = Ab + 8192;
        bf16x8 af[4], bg_[4];
#pragma unroll
        for (int m = 0; m < 4; ++m) {
            int row = wr * 64 + m * 16 + lr;
            af[m] = *(const bf16x8*)(Ab + row * 64 + SWZ(row, lg));
        }
#pragma unroll
        for (int n = 0; n < 4; ++n) {
            int row = wc * 64 + n * 16 + lr;
            bg_[n] = *(const bf16x8*)(Bb + row * 64 + SWZ(row, lg));
        }
#pragma unroll
        for (int m = 0; m < 4; ++m)
#pragma unroll
            for (int n = 0; n < 4; ++n)
                acc[m][n] = MFMA(af[m], bg_[n], acc[m][n], 0, 0, 0);
        __syncthreads();
    }

#pragma unroll
    for (int n = 0; n < 4; ++n) {
        int o = o0 + wc * 64 + n * 16 + lr;
        float bs = bias[o];
        int g = o >> 7, d = o & 127;
#pragma unroll
        for (int m = 0; m < 4; ++m) {
            int row = r0 + wr * 64 + m * 16 + lg * 4;
            int b = row >> 12, nn = row & (N_ - 1);
            if (mat == 0) {
#pragma unroll
                for (int j = 0; j < 4; ++j)
                    Q[((size_t)(b * G_ + g) * N_ + nn + j) * D_ + d] =
                        (bf16)((acc[m][n][j] + bs) * QSCALE);
            } else if (mat == 1) {
#pragma unroll
                for (int j = 0; j < 4; ++j)
                    K[((size_t)(b * G_ + g) * N_ + nn + j) * D_ + d] =
                        (bf16)(acc[m][n][j] + bs);
            } else {
                union { bf16 h[4]; uint2 u; } pk;
#pragma unroll
                for (int j = 0; j < 4; ++j) pk.h[j] = (bf16)(acc[m][n][j] + bs);
                *(uint2*)(Vt + ((size_t)(b * G_ + g) * D_ + d) * N_ + nn) = pk.u;
            }
        }
    }
}

// ================= shared attention tile body =================
struct AttnState {
    f32x16 oacc[4], lacc;
    float mrun;
};

template<typename T>
__device__ inline void attn_tile_body(AttnState& st, const bf16x8* aq,
                                      const bf16x8& ones, char* Kb, char* Vb,
                                      int l31, int h, T) {
    const float THR = 5.0f;
    f32x16 s0, s1;
#pragma unroll
    for (int r = 0; r < 16; ++r) { s0[r] = 0.f; s1[r] = 0.f; }
    __builtin_amdgcn_s_setprio(1);
#pragma unroll
    for (int kb = 0; kb < 8; ++kb) {
        int ch = (((kb << 1) | h) ^ (l31 & 15)) << 4;
        bf16x8 kf0 = *(const bf16x8*)(Kb + (size_t)l31 * 256 + ch);
        s0 = MFMA32(kf0, aq[kb], s0, 0, 0, 0);
        bf16x8 kf1 = *(const bf16x8*)(Kb + (size_t)(32 + l31) * 256 + ch);
        s1 = MFMA32(kf1, aq[kb], s1, 0, 0, 0);
    }
    __builtin_amdgcn_s_setprio(0);

    float x0 = max3f(s0[0],  s0[1],  s0[2]);
    float x1 = max3f(s0[3],  s0[4],  s0[5]);
    float x2 = max3f(s0[6],  s0[7],  s0[8]);
    float x3 = max3f(s0[9],  s0[10], s0[11]);
    float x4 = max3f(s0[12], s0[13], s0[14]);
    float x5 = max3f(s0[15], s1[0],  s1[1]);
    float x6 = max3f(s1[2],  s1[3],  s1[4]);
    float x7 = max3f(s1[5],  s1[6],  s1[7]);
    float x8 = max3f(s1[8],  s1[9],  s1[10]);
    float x9 = max3f(s1[11], s1[12], s1[13]);
    float xa = fmaxf(s1[14], s1[15]);
    float y0 = max3f(x0, x1, x2);
    float y1 = max3f(x3, x4, x5);
    float y2 = max3f(x6, x7, x8);
    float y3 = fmaxf(x9, xa);
    float mt = fmaxf(max3f(y0, y1, y2), y3);
    mt = fmaxf(mt, __shfl_xor(mt, 32));

    if (__any(mt > st.mrun + THR)) {
        float mn = fmaxf(st.mrun, mt);
        float corr = __builtin_amdgcn_exp2f(st.mrun - mn);
        st.mrun = mn;
#pragma unroll
        for (int r = 0; r < 16; ++r) {
            int qr = (r & 3) + 8 * (r >> 2) + 4 * h;
            float cr = __shfl(corr, qr);
            st.lacc[r] *= cr;
#pragma unroll
            for (int dt = 0; dt < 4; ++dt) st.oacc[dt][r] *= cr;
        }
    }

#pragma unroll
    for (int r = 0; r < 16; ++r) {
        s0[r] = __builtin_amdgcn_exp2f(s0[r] - st.mrun);
        s1[r] = __builtin_amdgcn_exp2f(s1[r] - st.mrun);
    }

    bf16x8 pa0, pa1, pa2, pa3;
    {
        unsigned u0 = pk2(s0[0], s0[1]),  v0 = pk2(s0[4], s0[5]);  pl32(u0, v0);
        unsigned u1 = pk2(s0[2], s0[3]),  v1 = pk2(s0[6], s0[7]);  pl32(u1, v1);
        pa0 = __builtin_bit_cast(bf16x8, (uint4){u0, u1, v0, v1});
        unsigned u2 = pk2(s0[8], s0[9]),  v2 = pk2(s0[12], s0[13]); pl32(u2, v2);
        unsigned u3 = pk2(s0[10], s0[11]), v3 = pk2(s0[14], s0[15]); pl32(u3, v3);
        pa1 = __builtin_bit_cast(bf16x8, (uint4){u2, u3, v2, v3});
        unsigned u4 = pk2(s1[0], s1[1]),  v4 = pk2(s1[4], s1[5]);  pl32(u4, v4);
        unsigned u5 = pk2(s1[2], s1[3]),  v5 = pk2(s1[6], s1[7]);  pl32(u5, v5);
        pa2 = __builtin_bit_cast(bf16x8, (uint4){u4, u5, v4, v5});
        unsigned u6 = pk2(s1[8], s1[9]),  v6 = pk2(s1[12], s1[13]); pl32(u6, v6);
        unsigned u7 = pk2(s1[10], s1[11]), v7 = pk2(s1[14], s1[15]); pl32(u7, v7);
        pa3 = __builtin_bit_cast(bf16x8, (uint4){u6, u7, v6, v7});
    }

    __builtin_amdgcn_s_setprio(1);
#pragma unroll
    for (int sl = 0; sl < 4; ++sl) {
        bf16x8 pa = (sl == 0) ? pa0 : (sl == 1) ? pa1 : (sl == 2) ? pa2 : pa3;
#pragma unroll
        for (int dt = 0; dt < 4; ++dt) {
            int row = dt * 16 + (l31 >> 1);
            int ch = ((((l31 & 1) << 3) + (sl << 1) + h) ^ (l31 >> 1)) << 4;
            bf16x8 vf = *(const bf16x8*)(Vb + (size_t)row * 256 + ch);
            st.oacc[dt] = MFMA32(pa, vf, st.oacc[dt], 0, 0, 0);
        }
        st.lacc = MFMA32(pa, ones, st.lacc, 0, 0, 0);
    }
    __builtin_amdgcn_s_setprio(0);
}

__device__ inline void attn_epilogue(AttnState& st, int sp, int bg, int q0,
                                     int l, int l31, int h,
                                     bf16* Op, float* ML) {
    float2* mlp = (float2*)ML + ((size_t)sp * 8 + bg) * N_ + q0;
#pragma unroll
    for (int r = 0; r < 16; ++r) {
        int qr = (r & 3) + 8 * (r >> 2) + 4 * h;
        float mv = __shfl(st.mrun, qr);
        if (l31 == 0) {
            float2 v; v.x = mv; v.y = st.lacc[r];
            mlp[qr] = v;
        }
    }
    bf16* op = Op + (((size_t)sp * 8 + bg) * N_ + q0) * D_;
#pragma unroll
    for (int dt = 0; dt < 4; ++dt)
#pragma unroll
        for (int r = 0; r < 16; ++r) {
            int qr = (r & 3) + 8 * (r >> 2) + 4 * h;
            op[(size_t)qr * D_ + dt * 32 + l31] = (bf16)st.oacc[dt][r];
        }
}

// ---------- kernel 4a: r13/r16 attention (64-kv tiles, static 64KB LDS) ----------
template<int SPLITS>
__global__ __launch_bounds__(512, 2) void attn_kernel(const bf16* __restrict__ Q,
                                                      const bf16* __restrict__ K,
                                                      const bf16* __restrict__ Vt,
                                                      bf16* __restrict__ XT,
                                                      bf16* __restrict__ Op,
                                                      float* __restrict__ ML) {
    __shared__ char smem[65536];
    const int tid = threadIdx.x;
    const int w = tid >> 6, l = tid & 63;
    const int l31 = l & 31, h = l >> 5;

    const int L = blockIdx.x;
    const int bg = L & 7;
    const int ix = L >> 3;
    const int sp = (SPLITS > 1) ? (ix >> 4) : 0;
    const int qb = (SPLITS > 1) ? (ix & 15) : ix;

    const bf16* Qh = Q + (size_t)bg * N_ * D_;
    const char* Kh = (const char*)(K + (size_t)bg * N_ * D_);
    const char* Vh = (const char*)(Vt + (size_t)bg * D_ * N_);
    const int q0 = qb * 256 + w * 32;
    const int kv0 = sp * (N_ / SPLITS);
    const int NT = N_ / SPLITS / 64;

    int offK[2], offV[2];
#pragma unroll
    for (int j = 0; j < 2; ++j) {
        int CL = (w * 2 + j) * 64 + l;
        int row = CL >> 4;
        int cp = (CL & 15) ^ (row & 15);
        offK[j] = row * 256 + cp * 16;
        int dv = 2 * row + (cp >> 3), k8 = cp & 7;
        offV[j] = dv * (N_ * 2) + k8 * 16;
    }

    bf16x8 aq[8];
#pragma unroll
    for (int kb = 0; kb < 8; ++kb)
        aq[kb] = *(const bf16x8*)(Qh + (size_t)(q0 + l31) * D_ + kb * 16 + h * 8);

    bf16 one_ = (bf16)1.0f;
    bf16x8 ones = {one_, one_, one_, one_, one_, one_, one_, one_};

    AttnState st;
#pragma unroll
    for (int dt = 0; dt < 4; ++dt)
#pragma unroll
        for (int r = 0; r < 16; ++r) st.oacc[dt][r] = 0.f;
#pragma unroll
    for (int r = 0; r < 16; ++r) st.lacc[r] = 0.f;
    st.mrun = -1e30f;

    auto STAGE = [&](int buf, int kv) {
        const char* pk = Kh + (size_t)kv * 256;
        const char* pv = Vh + (size_t)kv * 2;
        char* kb = smem + buf * 32768 + w * 2048;
        char* vb = smem + buf * 32768 + 16384 + w * 2048;
#pragma unroll
        for (int j = 0; j < 2; ++j) gload16(pk + offK[j], kb + j * 1024);
#pragma unroll
        for (int j = 0; j < 2; ++j) gload16(pv + offV[j], vb + j * 1024);
    };

    STAGE(0, kv0);

    for (int t = 0; t < NT; ++t) {
        int cur = t & 1;
        __builtin_amdgcn_s_barrier();
        if (t + 1 < NT) {
            STAGE(cur ^ 1, kv0 + (t + 1) * 64);
            asm volatile("s_waitcnt vmcnt(4)" ::: "memory");
        } else {
            asm volatile("s_waitcnt vmcnt(0)" ::: "memory");
        }
        __builtin_amdgcn_sched_barrier(0);
        __builtin_amdgcn_s_barrier();
        attn_tile_body(st, aq, ones, smem + cur * 32768,
                       smem + cur * 32768 + 16384, l31, h, 0);
    }

    if (SPLITS > 1) {
        attn_epilogue(st, sp, bg, q0, l, l31, h, Op, ML);
    } else {
        int b = bg >> 2, g = bg & 3;
#pragma unroll
        for (int r = 0; r < 16; ++r) {
            int qr = (r & 3) + 8 * (r >> 2) + 4 * h;
            float iv = 1.f / st.lacc[r];
#pragma unroll
            for (int dt = 0; dt < 4; ++dt)
                XT[((size_t)b * N_ + q0 + qr) * C_ + g * D_ + dt * 32 + l31] =
                    (bf16)(st.oacc[dt][r] * iv);
        }
    }
}

// ---------- kernel 4b: 128-kv staged tiles, dynamic 128KB LDS ----------
__global__ __launch_bounds__(512, 1) void attn_big_kernel(const bf16* __restrict__ Q,
                                                          const bf16* __restrict__ K,
                                                          const bf16* __restrict__ Vt,
                                                          bf16* __restrict__ Op,
                                                          float* __restrict__ ML) {
    extern __shared__ char smem[];
    const int tid = threadIdx.x;
    const int w = tid >> 6, l = tid & 63;
    const int l31 = l & 31, h = l >> 5;

    const int L = blockIdx.x;
    const int bg = L & 7;
    const int ix = L >> 3;
    const int sp = ix >> 4;
    const int qb = ix & 15;

    const bf16* Qh = Q + (size_t)bg * N_ * D_;
    const char* Kh = (const char*)(K + (size_t)bg * N_ * D_);
    const char* Vh = (const char*)(Vt + (size_t)bg * D_ * N_);
    const int q0 = qb * 256 + w * 32;
    const int kv0 = sp * (N_ / 2);
    const int NT = (N_ / 2) / 128;

    int offK[2], offV[2];
#pragma unroll
    for (int j = 0; j < 2; ++j) {
        int CL = (w * 2 + j) * 64 + l;
        int row = CL >> 4;
        int cp = (CL & 15) ^ (row & 15);
        offK[j] = row * 256 + cp * 16;
        int dv = 2 * row + (cp >> 3), k8 = cp & 7;
        offV[j] = dv * (N_ * 2) + k8 * 16;
    }

    bf16x8 aq[8];
#pragma unroll
    for (int kb = 0; kb < 8; ++kb)
        aq[kb] = *(const bf16x8*)(Qh + (size_t)(q0 + l31) * D_ + kb * 16 + h * 8);

    bf16 one_ = (bf16)1.0f;
    bf16x8 ones = {one_, one_, one_, one_, one_, one_, one_, one_};

    AttnState st;
#pragma unroll
    for (int dt = 0; dt < 4; ++dt)
#pragma unroll
        for (int r = 0; r < 16; ++r) st.oacc[dt][r] = 0.f;
#pragma unroll
    for (int r = 0; r < 16; ++r) st.lacc[r] = 0.f;
    st.mrun = -1e30f;

    auto STAGE = [&](int buf, int kv) {
#pragma unroll
        for (int s2 = 0; s2 < 2; ++s2) {
            const char* pk = Kh + (size_t)(kv + 64 * s2) * 256;
            const char* pv = Vh + (size_t)(kv + 64 * s2) * 2;
            char* kb = smem + buf * 65536 + s2 * 16384 + w * 2048;
            char* vb = smem + buf * 65536 + 32768 + s2 * 16384 + w * 2048;
#pragma unroll
            for (int j = 0; j < 2; ++j) gload16(pk + offK[j], kb + j * 1024);
#pragma unroll
            for (int j = 0; j < 2; ++j) gload16(pv + offV[j], vb + j * 1024);
        }
    };

    STAGE(0, kv0);

    for (int t = 0; t < NT; ++t) {
        int cur = t & 1;
        __builtin_amdgcn_s_barrier();
        if (t + 1 < NT) {
            STAGE(cur ^ 1, kv0 + (t + 1) * 128);
            asm volatile("s_waitcnt vmcnt(8)" ::: "memory");
        } else {
            asm volatile("s_waitcnt vmcnt(0)" ::: "memory");
        }
        __builtin_amdgcn_sched_barrier(0);
        __builtin_amdgcn_s_barrier();
#pragma unroll
        for (int s2 = 0; s2 < 2; ++s2)
            attn_tile_body(st, aq, ones,
                           smem + cur * 65536 + s2 * 16384,
                           smem + cur * 65536 + 32768 + s2 * 16384, l31, h, 0);
    }

    attn_epilogue(st, sp, bg, q0, l, l31, h, Op, ML);
}

// ---------- kernel 5: output projection + fused KV-split merge ----------
template<int FUSE>
__global__ __launch_bounds__(256) void oproj_kernel(const bf16* __restrict__ Ob,
                                                    const bf16* __restrict__ Op,
                                                    const float* __restrict__ ML,
                                                    const bf16* __restrict__ WB,
                                                    const float* __restrict__ bo,
                                                    const float* __restrict__ x,
                                                    float* __restrict__ out) {
    __shared__ char smem[24576];
    const int tid = threadIdx.x;
    const int w = tid >> 6, l = tid & 63;
    const int lr = l & 15, lg = l >> 4;
    const int wr = w >> 1, wc = w & 1;
    const bf16* W = WB + (size_t)3 * (C_ * C_);
    const int r0 = blockIdx.x * 128, o0 = blockIdx.y * 64;

    const char* srcA[2]; int dA[2], cpw[2]; size_t opRow[2];
    float w0f[2][4], w1f[2][4];
#pragma unroll
    for (int i = 0; i < 2; ++i) {
        int CL = tid + 256 * i, row = CL >> 2, c = CL & 3;
        cpw[i] = c ^ ((row >> 1) & 3);
        dA[i] = CL << 4;
        srcA[i] = (const char*)(Ob + (size_t)(r0 + row) * C_) + (cpw[i] << 4);
        if (FUSE) {
            int rg = r0 + row;
            int b = rg >> 12, n = rg & (N_ - 1);
            const float2* mlp = (const float2*)ML;
#pragma unroll
            for (int g = 0; g < 4; ++g) {
                int bg = b * 4 + g;
                float2 ml0 = mlp[(size_t)bg * N_ + n];
                float2 ml1 = mlp[(size_t)(8 + bg) * N_ + n];
                float mm = fmaxf(ml0.x, ml1.x);
                float a0 = __builtin_amdgcn_exp2f(ml0.x - mm);
                float a1 = __builtin_amdgcn_exp2f(ml1.x - mm);
                float inv = 1.f / (a0 * ml0.y + a1 * ml1.y);
                w0f[i][g] = a0 * inv;
                w1f[i][g] = a1 * inv;
            }
            opRow[i] = ((size_t)(b * 4) * N_ + n) * 256u;
        }
    }
    const char* srcB; int dB;
    {
        int CL = tid, row = CL >> 2, c = CL & 3;
        srcB = (const char*)(W + (size_t)(o0 + row) * C_) + SWZ(row, c);
        dB = 8192 + (CL << 4);
    }

    f32x4 z = {0.f, 0.f, 0.f, 0.f};
    f32x4 acc[4][2];
#pragma unroll
    for (int m = 0; m < 4; ++m) { acc[m][0] = z; acc[m][1] = z; }

    uint4 a0r[2], a1r[2];
    auto LOAD_A = [&](int kt) {
        int g = kt >> 2;
#pragma unroll
        for (int i = 0; i < 2; ++i) {
            size_t off = opRow[i] + (size_t)g * ((size_t)N_ * 256u - 256u)
                       + (size_t)(kt * 64) + ((size_t)cpw[i] << 4);
            a0r[i] = *(const uint4*)((const char*)Op + off);
            a1r[i] = *(const uint4*)((const char*)Op + 8388608u + off);
        }
    };
    auto WRITE_A = [&](int buf, int kt) {
        int g = kt >> 2;
        char* base = smem + buf * 12288;
#pragma unroll
        for (int i = 0; i < 2; ++i) {
            union { uint4 u; bf16 h[8]; } u0, u1, uo;
            u0.u = a0r[i]; u1.u = a1r[i];
#pragma unroll
            for (int e = 0; e < 8; ++e)
                uo.h[e] = (bf16)(w0f[i][g] * (float)u0.h[e] + w1f[i][g] * (float)u1.h[e]);
            *(uint4*)(base + dA[i]) = uo.u;
        }
    };
    auto STAGE_A_PLAIN = [&](int buf, int kt) {
        char* base = smem + buf * 12288;
#pragma unroll
        for (int i = 0; i < 2; ++i) gload16(srcA[i] + kt * 64, base + dA[i]);
    };
    auto STAGE_B = [&](int buf, int kt) {
        gload16(srcB + kt * 64, smem + buf * 12288 + dB);
    };

    STAGE_B(0, 0);
    if (FUSE) { LOAD_A(0); WRITE_A(0, 0); }
    else       STAGE_A_PLAIN(0, 0);
    __syncthreads();

    for (int t = 0; t < 16; ++t) {
        int cur = t & 1;
        if (t < 15) {
            STAGE_B(cur ^ 1, t + 1);
            if (FUSE) LOAD_A(t + 1);
            else      STAGE_A_PLAIN(cur ^ 1, t + 1);
        }
        char* Ab = smem + cur * 12288;
        char* Bb = Ab + 8192;
        bf16x8 af[4], bg_[2];
#pragma unroll
        for (int m = 0; m < 4; ++m) {
            int row = wr * 64 + m * 16 + lr;
            af[m] = *(const bf16x8*)(Ab + row * 64 + SWZ(row, lg));
        }
#pragma unroll
        for (int n = 0; n < 2; ++n) {
            int row = wc * 32 + n * 16 + lr;
            bg_[n] = *(const bf16x8*)(Bb + row * 64 + SWZ(row, lg));
        }
#pragma unroll
        for (int m = 0; m < 4; ++m)
#pragma unroll
            for (int n = 0; n < 2; ++n)
                acc[m][n] = MFMA(af[m], bg_[n], acc[m][n], 0, 0, 0);
        if (FUSE && t < 15) WRITE_A(cur ^ 1, t + 1);
        __syncthreads();
    }

#pragma unroll
    for (int n = 0; n < 2; ++n) {
        int o = o0 + wc * 32 + n * 16 + lr;
        float bs = bo[o];
#pragma unroll
        for (int m = 0; m < 4; ++m) {
            int row = r0 + wr * 64 + m * 16 + lg * 4;
            int b = row >> 12, nn = row & (N_ - 1);
            size_t base = ((size_t)b * C_ + o) * N_ + nn;
            float4 xv = *(const float4*)(x + base);
            float4 ov;
            ov.x = acc[m][n][0] + bs + xv.x;
            ov.y = acc[m][n][1] + bs + xv.y;
            ov.z = acc[m][n][2] + bs + xv.z;
            ov.w = acc[m][n][3] + bs + xv.w;
            *(float4*)(out + base) = ov;
        }
    }
}

extern "C" void kernel_launch(void* const* d_in, const int* in_sizes, int n_in,
                              void* d_out, int out_size, void* d_ws, size_t ws_size,
                              hipStream_t stream) {
    const float* x  = (const float*)d_in[0];
    const float* Wq = (const float*)d_in[1];
    const float* bq = (const float*)d_in[2];
    const float* Wk = (const float*)d_in[3];
    const float* bk = (const float*)d_in[4];
    const float* Wv = (const float*)d_in[5];
    const float* bv = (const float*)d_in[6];
    const float* Wo = (const float*)d_in[7];
    const float* bo = (const float*)d_in[8];

    char* ws = (char*)d_ws;
    bf16* Q   = (bf16*)(ws + OFF_Q);
    bf16* K   = (bf16*)(ws + OFF_K);
    bf16* Vt  = (bf16*)(ws + OFF_VT);
    bf16* XT  = (bf16*)(ws + OFF_XT);
    bf16* WB  = (bf16*)(ws + OFF_WB);
    bf16* Op  = (bf16*)(ws + OFF_OP);
    float* ML = (float*)(ws + OFF_ML);
    float* out = (float*)d_out;

    hipLaunchKernelGGL(prep_kernel, dim3(2048), dim3(256), 0, stream,
                       Wq, Wk, Wv, Wo, WB, x, XT);
    hipLaunchKernelGGL(qkv_kernel, dim3(64, 4, 3), dim3(256), 0, stream,
                       XT, WB, bq, bk, bv, Q, K, Vt);
    if (ws_size >= (size_t)WS_NEED_SPLIT) {
        hipError_t e = hipFuncSetAttribute(
            reinterpret_cast<const void*>(&attn_big_kernel),
            hipFuncAttributeMaxDynamicSharedMemorySize, 131072);
        if (e == hipSuccess) {
            hipLaunchKernelGGL(attn_big_kernel, dim3(256), dim3(512), 131072, stream,
                               Q, K, Vt, Op, ML);
        } else {
            hipLaunchKernelGGL(attn_kernel<2>, dim3(256), dim3(512), 0, stream,
                               Q, K, Vt, XT, Op, ML);
        }
        hipLaunchKernelGGL(oproj_kernel<1>, dim3(64, 8), dim3(256), 0, stream,
                           XT, Op, ML, WB, bo, x, out);
    } else {
        hipLaunchKernelGGL(attn_kernel<1>, dim3(128), dim3(512), 0, stream,
                           Q, K, Vt, XT, Op, ML);
        hipLaunchKernelGGL(oproj_kernel<0>, dim3(64, 8), dim3(256), 0, stream,
                           XT, Op, ML, WB, bo, x, out);
    }
}